// Round 1
// baseline (12048.291 us; speedup 1.0000x reference)
//
#include <hip/hip_runtime.h>
#include <math.h>

constexpr int B_   = 64;
constexpr int L_   = 30;
constexpr int P_   = 196;
constexpr int ENC_ = 2048;
constexpr int V_   = 10000;
constexpr int XSTR = 3072;   // X row: [ctx 2048 | emb 512 | h 512]
constexpr unsigned NB = 256; // persistent grid size (1 block/CU)

__device__ __forceinline__ float wred_sum(float v) {
#pragma unroll
    for (int m = 32; m >= 1; m >>= 1) v += __shfl_xor(v, m, 64);
    return v;
}
__device__ __forceinline__ float sigmf(float x) { return 1.0f / (1.0f + expf(-x)); }
// 16-term dot: w[4] (registers) . x[16] (pointer, 16B-aligned)
__device__ __forceinline__ float dot16(const float4* w, const float* xp) {
    const float4* x4 = (const float4*)xp;
    float4 x0 = x4[0], x1 = x4[1], x2 = x4[2], x3 = x4[3];
    float s = w[0].x * x0.x;
    s = fmaf(w[0].y, x0.y, s); s = fmaf(w[0].z, x0.z, s); s = fmaf(w[0].w, x0.w, s);
    s = fmaf(w[1].x, x1.x, s); s = fmaf(w[1].y, x1.y, s);
    s = fmaf(w[1].z, x1.z, s); s = fmaf(w[1].w, x1.w, s);
    s = fmaf(w[2].x, x2.x, s); s = fmaf(w[2].y, x2.y, s);
    s = fmaf(w[2].z, x2.z, s); s = fmaf(w[2].w, x2.w, s);
    s = fmaf(w[3].x, x3.x, s); s = fmaf(w[3].y, x3.y, s);
    s = fmaf(w[3].z, x3.z, s); s = fmaf(w[3].w, x3.w, s);
    return s;
}

// ---------------------------------------------------------------------------
// software grid barrier: bar[0]=arrival counter, bar[1]=generation.
// Leader-only arrival (1 atomic/block) + leader-only relaxed poll, acquire
// fence on exit. agent scope => cross-XCD visibility (L2 wb/inv handled by
// the atomic/fence lowering). cnt self-resets => reusable across launches
// (k_init zeroes it each launch anyway).
// ---------------------------------------------------------------------------
__device__ __forceinline__ void gsync(unsigned* bar) {
    __syncthreads();
    if (threadIdx.x == 0) {
        unsigned g = __hip_atomic_load(&bar[1], __ATOMIC_RELAXED, __HIP_MEMORY_SCOPE_AGENT);
        unsigned arr = __hip_atomic_fetch_add(&bar[0], 1u, __ATOMIC_ACQ_REL, __HIP_MEMORY_SCOPE_AGENT);
        if (arr == NB - 1u) {
            __hip_atomic_store(&bar[0], 0u, __ATOMIC_RELAXED, __HIP_MEMORY_SCOPE_AGENT);
            __hip_atomic_fetch_add(&bar[1], 1u, __ATOMIC_RELEASE, __HIP_MEMORY_SCOPE_AGENT);
        } else {
            while (__hip_atomic_load(&bar[1], __ATOMIC_RELAXED, __HIP_MEMORY_SCOPE_AGENT) == g)
                __builtin_amdgcn_s_sleep(2);
            __threadfence();   // acquire: invalidate L1/L2 so other XCDs' writes are seen
        }
    }
    __syncthreads();
}

// ---------------------------------------------------------------------------
// k_init: mean over P  (+ zero the grid barrier).  grid=(8,64), 256 thr.
// ---------------------------------------------------------------------------
__global__ __launch_bounds__(256) void k_init(const float* __restrict__ enc,
                                              float* __restrict__ mean,
                                              unsigned* __restrict__ bar) {
    if (blockIdx.x == 0 && blockIdx.y == 0 && threadIdx.x == 0) {
        bar[0] = 0u; bar[1] = 0u;
    }
    int dc = blockIdx.x, b = blockIdx.y, d = dc * 256 + threadIdx.x;
    const float* base = enc + (size_t)b * P_ * ENC_ + d;
    float s = 0.f;
    for (int p = 0; p < P_; p++) s += base[(size_t)p * ENC_];
    mean[(size_t)b * ENC_ + d] = s / 196.0f;
}

// ---------------------------------------------------------------------------
// k_big: fp32 GEMM, 128x128 tile, BK=16, split 8x8 micro-tile. (unchanged)
// blocks 0..391: att1 = enc @ We^T ; 392..395: h0 -> X h-slot ; 396..399: c0.
// ---------------------------------------------------------------------------
__global__ __launch_bounds__(256) void k_big(
    const float* __restrict__ enc, const float* __restrict__ mean,
    const float* __restrict__ We, const float* __restrict__ be,
    const float* __restrict__ Wh0, const float* __restrict__ bh0,
    const float* __restrict__ Wc0, const float* __restrict__ bc0,
    float* __restrict__ att1, float* __restrict__ X, float* __restrict__ cbuf) {
    __shared__ __align__(16) float As[16][132];
    __shared__ __align__(16) float Ws[16][132];
    int gx = blockIdx.x;
    const float *A, *W, *bias;
    float* C;
    int m0, n0, Mtot, cstr;
    if (gx < 392) {
        A = enc; W = We; bias = be; C = att1;
        m0 = (gx >> 2) * 128; n0 = (gx & 3) * 128; Mtot = 12544; cstr = 512;
    } else if (gx < 396) {
        A = mean; W = Wh0; bias = bh0; C = X + 2560;
        m0 = 0; n0 = (gx - 392) * 128; Mtot = 64; cstr = XSTR;
    } else {
        A = mean; W = Wc0; bias = bc0; C = cbuf;
        m0 = 0; n0 = (gx - 396) * 128; Mtot = 64; cstr = 512;
    }
    int tid = threadIdx.x, tx = tid & 15, ty = tid >> 4;
    int srow = tid >> 2, skq = tid & 3;
    float acc[2][2][4][4] = {};
    int r0 = m0 + min(srow, Mtot - 1);
    int r1 = m0 + min(srow + 64, Mtot - 1);
    const float* a0p = A + (size_t)r0 * 2048 + skq * 4;
    const float* a1p = A + (size_t)r1 * 2048 + skq * 4;
    const float* w0p = W + (size_t)(n0 + srow) * 2048 + skq * 4;
    const float* w1p = W + (size_t)(n0 + srow + 64) * 2048 + skq * 4;
    for (int kk = 0; kk < 2048; kk += 16) {
        float4 a0v = *(const float4*)(a0p + kk);
        float4 a1v = *(const float4*)(a1p + kk);
        float4 w0v = *(const float4*)(w0p + kk);
        float4 w1v = *(const float4*)(w1p + kk);
        __syncthreads();
        As[skq * 4 + 0][srow] = a0v.x; As[skq * 4 + 1][srow] = a0v.y;
        As[skq * 4 + 2][srow] = a0v.z; As[skq * 4 + 3][srow] = a0v.w;
        As[skq * 4 + 0][srow + 64] = a1v.x; As[skq * 4 + 1][srow + 64] = a1v.y;
        As[skq * 4 + 2][srow + 64] = a1v.z; As[skq * 4 + 3][srow + 64] = a1v.w;
        Ws[skq * 4 + 0][srow] = w0v.x; Ws[skq * 4 + 1][srow] = w0v.y;
        Ws[skq * 4 + 2][srow] = w0v.z; Ws[skq * 4 + 3][srow] = w0v.w;
        Ws[skq * 4 + 0][srow + 64] = w1v.x; Ws[skq * 4 + 1][srow + 64] = w1v.y;
        Ws[skq * 4 + 2][srow + 64] = w1v.z; Ws[skq * 4 + 3][srow + 64] = w1v.w;
        __syncthreads();
#pragma unroll
        for (int k = 0; k < 16; k++) {
            float4 av0 = *(const float4*)&As[k][ty * 4];
            float4 av1 = *(const float4*)&As[k][64 + ty * 4];
            float4 bv0 = *(const float4*)&Ws[k][tx * 4];
            float4 bv1 = *(const float4*)&Ws[k][64 + tx * 4];
            float ar[2][4] = {{av0.x, av0.y, av0.z, av0.w}, {av1.x, av1.y, av1.z, av1.w}};
            float br[2][4] = {{bv0.x, bv0.y, bv0.z, bv0.w}, {bv1.x, bv1.y, bv1.z, bv1.w}};
#pragma unroll
            for (int ih = 0; ih < 2; ih++)
#pragma unroll
                for (int jh = 0; jh < 2; jh++)
#pragma unroll
                    for (int i = 0; i < 4; i++)
#pragma unroll
                        for (int j = 0; j < 4; j++)
                            acc[ih][jh][i][j] = fmaf(ar[ih][i], br[jh][j], acc[ih][jh][i][j]);
        }
    }
#pragma unroll
    for (int ih = 0; ih < 2; ih++)
#pragma unroll
        for (int i = 0; i < 4; i++) {
            int m = m0 + ih * 64 + ty * 4 + i;
            if (m - m0 < Mtot) {
#pragma unroll
                for (int jh = 0; jh < 2; jh++) {
                    int n = n0 + jh * 64 + tx * 4;
                    float4 o;
                    o.x = acc[ih][jh][i][0] + bias[n + 0];
                    o.y = acc[ih][jh][i][1] + bias[n + 1];
                    o.z = acc[ih][jh][i][2] + bias[n + 2];
                    o.w = acc[ih][jh][i][3] + bias[n + 3];
                    *(float4*)(C + (size_t)m * cstr + n) = o;
                }
            }
        }
}

// ---------------------------------------------------------------------------
// k_emb0: X emb-slot <- emb[dec_in[:,0]].  grid=64, 256 thr.
// ---------------------------------------------------------------------------
__global__ __launch_bounds__(256) void k_emb0(const float* __restrict__ emb,
                                              const int* __restrict__ dec,
                                              float* __restrict__ X) {
    int b = blockIdx.x, tid = threadIdx.x;
    int tok = dec[b * L_];
    X[(size_t)b * XSTR + 2048 + tid] = emb[(size_t)tok * 512 + tid];
    X[(size_t)b * XSTR + 2048 + 256 + tid] = emb[(size_t)tok * 512 + 256 + tid];
}

// ===========================================================================
// Persistent mega-kernel phases. Grid = 256 blocks x 256 thr (4 waves/block).
// ===========================================================================

// att2[b][n] = bd[n] + h[b].Wd[n]  — blocks 157..172 (64 waves: nt(8) x bg(8))
__device__ __forceinline__ void ph_att2(int bid, int wid, int lane,
                                        const float* X, const float* Wd,
                                        const float* bd, float* att2) {
    if (bid < 157 || bid >= 173) return;
    int task = (bid - 157) * 4 + wid;  // [0,64)
    int nt = task >> 3, bg = task & 7;
    int n = nt * 64 + lane;
    const float* wrow = Wd + (size_t)n * 512;
    const float* xbase = X + 2560 + (size_t)bg * 8 * XSTR;
    float acc[8];
#pragma unroll
    for (int b = 0; b < 8; b++) acc[b] = 0.f;
#pragma unroll 1
    for (int k16 = 0; k16 < 512; k16 += 16) {
        float4 w[4];
        w[0] = *(const float4*)(wrow + k16);
        w[1] = *(const float4*)(wrow + k16 + 4);
        w[2] = *(const float4*)(wrow + k16 + 8);
        w[3] = *(const float4*)(wrow + k16 + 12);
        const float* xc = xbase + k16;
#pragma unroll
        for (int b = 0; b < 8; b++)
            acc[b] += dot16(w, xc + (size_t)b * XSTR);
    }
    float bias = bd[n];
#pragma unroll
    for (int b = 0; b < 8; b++)
        att2[(size_t)(bg * 8 + b) * 512 + n] = acc[b] + bias;
}

// e[b][p] = bf + sum_n relu(att1+att2)*Wf — blocks 16..255 (960 waves; wave
// handles one b, p = ps, ps+15, ...)
__device__ __forceinline__ void ph_e(int bid, int wid, int lane,
                                     const float* att1, const float* att2,
                                     const float* Wf, const float* bfp,
                                     float* ebuf) {
    if (bid < 16) return;
    int wv = (bid - 16) * 4 + wid;  // [0,960)
    int b = wv & 63, ps = wv >> 6;  // ps in [0,15)
    const float4* a24 = (const float4*)(att2 + (size_t)b * 512);
    float4 t0 = a24[lane], t1 = a24[lane + 64];
    const float4* wf4 = (const float4*)Wf;
    float4 f0 = wf4[lane], f1 = wf4[lane + 64];
    float bfv = bfp[0];
    for (int p = ps; p < P_; p += 15) {
        const float4* rr = (const float4*)(att1 + ((size_t)b * P_ + p) * 512);
        float4 v0 = rr[lane], v1 = rr[lane + 64];
        float s = fmaxf(v0.x + t0.x, 0.f) * f0.x + fmaxf(v0.y + t0.y, 0.f) * f0.y +
                  fmaxf(v0.z + t0.z, 0.f) * f0.z + fmaxf(v0.w + t0.w, 0.f) * f0.w +
                  fmaxf(v1.x + t1.x, 0.f) * f1.x + fmaxf(v1.y + t1.y, 0.f) * f1.y +
                  fmaxf(v1.z + t1.z, 0.f) * f1.z + fmaxf(v1.w + t1.w, 0.f) * f1.w;
        s = wred_sum(s);
        if (lane == 0) ebuf[b * 256 + p] = s + bfv;
    }
}

// softmax(e) (block-local, 4x redundant per b) + ctx = att@enc -> X ctx-slot.
// all 256 blocks: b = bid>>2, dc = bid&3 (512 cols each, float2/thread).
__device__ __forceinline__ void ph_ctx(int bid, int tid, const float* enc,
                                       const float* ebuf, float* atts_out,
                                       float* X, int t,
                                       float* s_att, float* s_red) {
    int b = bid >> 2, dc = bid & 3;
    float val = (tid < P_) ? ebuf[b * 256 + tid] : -INFINITY;
    s_red[tid] = val;
    __syncthreads();
    for (int s = 128; s > 0; s >>= 1) {
        if (tid < s) s_red[tid] = fmaxf(s_red[tid], s_red[tid + s]);
        __syncthreads();
    }
    float m = s_red[0];
    __syncthreads();
    float ex = (tid < P_) ? expf(val - m) : 0.f;
    s_red[tid] = ex;
    __syncthreads();
    for (int s = 128; s > 0; s >>= 1) {
        if (tid < s) s_red[tid] += s_red[tid + s];
        __syncthreads();
    }
    float sum = s_red[0];
    if (tid < P_) {
        float att = ex / sum;
        s_att[tid] = att;
        if (dc == 0) atts_out[((size_t)b * L_ + t) * P_ + tid] = att;
    }
    __syncthreads();
    int d = dc * 512 + tid * 2;
    const float* base = enc + (size_t)b * P_ * ENC_ + d;
    float a0 = 0, a1 = 0, a2 = 0, a3 = 0;
    float c0 = 0, c1 = 0, c2 = 0, c3 = 0;
#pragma unroll 1
    for (int p = 0; p < P_; p += 4) {
        float w0 = s_att[p + 0], w1 = s_att[p + 1];
        float w2 = s_att[p + 2], w3 = s_att[p + 3];
        float2 v0 = *(const float2*)(base + (size_t)(p + 0) * ENC_);
        float2 v1 = *(const float2*)(base + (size_t)(p + 1) * ENC_);
        float2 v2 = *(const float2*)(base + (size_t)(p + 2) * ENC_);
        float2 v3 = *(const float2*)(base + (size_t)(p + 3) * ENC_);
        a0 = fmaf(w0, v0.x, a0); c0 = fmaf(w0, v0.y, c0);
        a1 = fmaf(w1, v1.x, a1); c1 = fmaf(w1, v1.y, c1);
        a2 = fmaf(w2, v2.x, a2); c2 = fmaf(w2, v2.y, c2);
        a3 = fmaf(w3, v3.x, a3); c3 = fmaf(w3, v3.y, c3);
    }
    float2 o;
    o.x = (a0 + a1) + (a2 + a3);
    o.y = (c0 + c1) + (c2 + c3);
    *(float2*)(X + (size_t)b * XSTR + d) = o;
}

// gate partials: wave-task (nt in 32, kc in kcT), acc[64] over batch.
__device__ __forceinline__ void ph_gates(int bid, int wid, int lane,
                                         const float* X, const float* Wih,
                                         const float* Whh, float* pg,
                                         int kcT, int chunk) {
    int wt = bid * 4 + wid;
    if (wt >= 32 * kcT) return;
    int nt = wt & 31, kc = wt >> 5;
    int row = nt * 64 + lane;
    const float* wih_row = Wih + (size_t)row * 2560;
    const float* whh_row = Whh + (size_t)row * 512;
    int kbase = kc * chunk;
    const float* xbase = X + kbase;
    float acc[64];
#pragma unroll
    for (int b = 0; b < 64; b++) acc[b] = 0.f;
#pragma unroll 1
    for (int k16 = 0; k16 < chunk; k16 += 16) {
        int kk = kbase + k16;
        const float* wr = (kk < 2560) ? (wih_row + kk) : (whh_row + (kk - 2560));
        float4 w[4];
        w[0] = *(const float4*)(wr);
        w[1] = *(const float4*)(wr + 4);
        w[2] = *(const float4*)(wr + 8);
        w[3] = *(const float4*)(wr + 12);
        const float* xc = xbase + k16;
#pragma unroll
        for (int b = 0; b < 64; b++)
            acc[b] += dot16(w, xc + (size_t)b * XSTR);
    }
#pragma unroll
    for (int b = 0; b < 64; b++)
        pg[((size_t)kc * 64 + b) * 2048 + row] = acc[b];
}

// lstm cell: blocks 0..127, b = bid>>1, j = (bid&1)*256+tid.
__device__ __forceinline__ void ph_lstm(int bid, int tid, const float* pg,
                                        const float* bih, const float* bhh,
                                        float* X, float* cbuf, int kcT) {
    if (bid >= 128) return;
    int b = bid >> 1, j = (bid & 1) * 256 + tid;
    float g[4];
#pragma unroll
    for (int gi = 0; gi < 4; gi++) {
        int n = gi * 512 + j;
        float s = bih[n] + bhh[n];
        for (int kc = 0; kc < kcT; kc++)
            s += pg[((size_t)kc * 64 + b) * 2048 + n];
        g[gi] = s;
    }
    float c = cbuf[b * 512 + j];
    float cn = sigmf(g[1]) * c + sigmf(g[0]) * tanhf(g[2]);
    float hn = sigmf(g[3]) * tanhf(cn);
    cbuf[b * 512 + j] = cn;
    X[(size_t)b * XSTR + 2560 + j] = hn;
}

// logits: blocks 0..156 (nt=bid, bg=wid), acc[16] over batch group.
__device__ __forceinline__ void ph_logits(int bid, int wid, int lane,
                                          const float* X, const float* Wv,
                                          const float* bv, float* out, int t) {
    if (bid >= 157) return;
    int nt = bid, bg = wid;
    int v = nt * 64 + lane;
    int vr = min(v, V_ - 1);
    const float* wrow = Wv + (size_t)vr * 512;
    const float* xbase = X + 2560 + (size_t)bg * 16 * XSTR;
    float acc[16];
#pragma unroll
    for (int b = 0; b < 16; b++) acc[b] = 0.f;
#pragma unroll 1
    for (int k16 = 0; k16 < 512; k16 += 16) {
        float4 w[4];
        w[0] = *(const float4*)(wrow + k16);
        w[1] = *(const float4*)(wrow + k16 + 4);
        w[2] = *(const float4*)(wrow + k16 + 8);
        w[3] = *(const float4*)(wrow + k16 + 12);
        const float* xc = xbase + k16;
#pragma unroll
        for (int b = 0; b < 16; b++)
            acc[b] += dot16(w, xc + (size_t)b * XSTR);
    }
    if (v < V_) {
        float bias = bv[v];
#pragma unroll
        for (int b = 0; b < 16; b++) {
            int bb = bg * 16 + b;
            out[((size_t)bb * L_ + t) * V_ + v] = acc[b] + bias;
        }
    }
}

// argmax(logits) + emb gather -> X emb-slot.  blocks 0..15, wave = one b.
__device__ __forceinline__ void ph_fin(int bid, int wid, int lane,
                                       const float* out, const float* emb,
                                       float* X, int t) {
    if (bid >= 16) return;
    int b = bid * 4 + wid;
    const float* orow = out + ((size_t)b * L_ + t) * V_;
    float best = -INFINITY;
    int bi = 0;
    for (int v = lane; v < V_; v += 64) {
        float s = orow[v];
        if (s > best) { best = s; bi = v; }
    }
#pragma unroll
    for (int m = 32; m >= 1; m >>= 1) {
        float ob = __shfl_xor(best, m, 64);
        int oi = __shfl_xor(bi, m, 64);
        if (ob > best || (ob == best && oi < bi)) { best = ob; bi = oi; }
    }
    const float4* e4 = (const float4*)(emb + (size_t)bi * 512);
    float4* x4 = (float4*)(X + (size_t)b * XSTR + 2048);
    x4[lane] = e4[lane];
    x4[lane + 64] = e4[lane + 64];
}

// ---------------------------------------------------------------------------
// k_mega: the entire 30-step decode loop, persistent, 5 grid syncs/step.
// Overlaps {logits_t || att2_{t+1}} and {fin_t || e_{t+1}} (independent
// dependence chains between lstm_t and gates_{t+1}).
// ---------------------------------------------------------------------------
__global__ __launch_bounds__(256) void k_mega(
    const float* __restrict__ enc, const float* __restrict__ emb,
    const float* __restrict__ Wd, const float* __restrict__ bd,
    const float* __restrict__ Wf, const float* __restrict__ bfp,
    const float* __restrict__ Wih, const float* __restrict__ bih,
    const float* __restrict__ Whh, const float* __restrict__ bhh,
    const float* __restrict__ Wv, const float* __restrict__ bv,
    const float* __restrict__ att1, float* __restrict__ X,
    float* __restrict__ cbuf, float* __restrict__ att2,
    float* __restrict__ ebuf, float* __restrict__ pg,
    float* __restrict__ out, float* __restrict__ atts_out,
    unsigned* __restrict__ bar, int kcT, int chunk) {
    const int bid = blockIdx.x, tid = threadIdx.x;
    const int wid = tid >> 6, lane = tid & 63;
    __shared__ float s_att[256];
    __shared__ float s_red[256];

    // prologue: att2_0 -> e_0 -> softmax+ctx_0
    ph_att2(bid, wid, lane, X, Wd, bd, att2);
    gsync(bar);
    ph_e(bid, wid, lane, att1, att2, Wf, bfp, ebuf);
    gsync(bar);
    ph_ctx(bid, tid, enc, ebuf, atts_out, X, 0, s_att, s_red);
    gsync(bar);

#pragma unroll 1
    for (int t = 0; t < L_; ++t) {
        ph_gates(bid, wid, lane, X, Wih, Whh, pg, kcT, chunk);
        gsync(bar);
        ph_lstm(bid, tid, pg, bih, bhh, X, cbuf, kcT);
        gsync(bar);
        ph_logits(bid, wid, lane, X, Wv, bv, out, t);
        if (t < L_ - 1) ph_att2(bid, wid, lane, X, Wd, bd, att2);
        if (t == L_ - 1) break;   // uniform exit: logits_29 flushed at kernel end
        gsync(bar);
        ph_fin(bid, wid, lane, out, emb, X, t);
        ph_e(bid, wid, lane, att1, att2, Wf, bfp, ebuf);
        gsync(bar);
        ph_ctx(bid, tid, enc, ebuf, atts_out, X, t + 1, s_att, s_red);
        gsync(bar);
    }
}

// ---------------------------------------------------------------------------
extern "C" void kernel_launch(void* const* d_in, const int* in_sizes, int n_in,
                              void* d_out, int out_size, void* d_ws, size_t ws_size,
                              hipStream_t stream) {
    const float* enc = (const float*)d_in[0];
    const int* dec   = (const int*)d_in[1];
    const float* emb = (const float*)d_in[3];
    const float* We  = (const float*)d_in[4];
    const float* be  = (const float*)d_in[5];
    const float* Wd  = (const float*)d_in[6];
    const float* bd  = (const float*)d_in[7];
    const float* Wf  = (const float*)d_in[8];
    const float* bf  = (const float*)d_in[9];
    const float* Wih = (const float*)d_in[10];
    const float* bih = (const float*)d_in[11];
    const float* Whh = (const float*)d_in[12];
    const float* bhh = (const float*)d_in[13];
    const float* Wh0 = (const float*)d_in[14];
    const float* bh0 = (const float*)d_in[15];
    const float* Wc0 = (const float*)d_in[16];
    const float* bc0 = (const float*)d_in[17];
    const float* Wv  = (const float*)d_in[18];
    const float* bv  = (const float*)d_in[19];

    float* out = (float*)d_out;
    float* ws = (float*)d_ws;

    // workspace layout (floats)
    float* att1 = ws;                  // 6,422,528
    float* X    = att1 + 6422528;      //   196,608
    float* cbuf = X + 196608;          //    32,768
    float* att2 = cbuf + 32768;        //    32,768
    float* ebuf = att2 + 32768;        //    16,384 (64 x 256, P padded)
    unsigned* bar = (unsigned*)(ebuf + 16384);  // 256-float slot (2 used)
    float* pg   = ws + 6701312;        // kcT * 131,072 gate partials
    float* mean = pg;                  // alias: only live before k_mega

    const size_t base_fl = 6701312;
    size_t avail_fl = ws_size / 4;
    int kcT = 2, chunk = 1536;
    const int opt_kc[6] = {32, 24, 16, 8, 4, 2};
    for (int i = 0; i < 6; i++) {
        if (avail_fl >= base_fl + (size_t)opt_kc[i] * 131072) {
            kcT = opt_kc[i];
            chunk = 3072 / kcT;
            break;
        }
    }

    float* atts_out = out + (size_t)B_ * L_ * V_;

    hipLaunchKernelGGL(k_init, dim3(8, 64), dim3(256), 0, stream, enc, mean, bar);
    hipLaunchKernelGGL(k_big, dim3(400), dim3(256), 0, stream, enc, mean, We, be,
                       Wh0, bh0, Wc0, bc0, att1, X, cbuf);
    hipLaunchKernelGGL(k_emb0, dim3(64), dim3(256), 0, stream, emb, dec, X);
    hipLaunchKernelGGL(k_mega, dim3(NB), dim3(256), 0, stream,
                       enc, emb, Wd, bd, Wf, bf, Wih, bih, Whh, bhh, Wv, bv,
                       att1, X, cbuf, att2, ebuf, pg, out, atts_out, bar,
                       kcT, chunk);
}

// Round 2
// 7232.434 us; speedup vs baseline: 1.6659x; 1.6659x over previous
//
#include <hip/hip_runtime.h>
#include <math.h>

constexpr int B_   = 64;
constexpr int L_   = 30;
constexpr int P_   = 196;
constexpr int ENC_ = 2048;
constexpr int V_   = 10000;
constexpr int XSTR = 3072;   // X row: [ctx 2048 | emb 512 | h 512]
constexpr unsigned NB = 256; // persistent grid size (1 block/CU)
constexpr int SUBCH = 512;   // gates staging sub-chunk (floats)

__device__ __forceinline__ float wred_sum(float v) {
#pragma unroll
    for (int m = 32; m >= 1; m >>= 1) v += __shfl_xor(v, m, 64);
    return v;
}
__device__ __forceinline__ float sigmf(float x) { return 1.0f / (1.0f + expf(-x)); }

// 16-term dot: w[4] (registers) . x[16] (pointer, 16B-aligned; global or LDS)
__device__ __forceinline__ float dot16(const float4* w, const float* xp) {
    const float4* x4 = (const float4*)xp;
    float4 x0 = x4[0], x1 = x4[1], x2 = x4[2], x3 = x4[3];
    float s = w[0].x * x0.x;
    s = fmaf(w[0].y, x0.y, s); s = fmaf(w[0].z, x0.z, s); s = fmaf(w[0].w, x0.w, s);
    s = fmaf(w[1].x, x1.x, s); s = fmaf(w[1].y, x1.y, s);
    s = fmaf(w[1].z, x1.z, s); s = fmaf(w[1].w, x1.w, s);
    s = fmaf(w[2].x, x2.x, s); s = fmaf(w[2].y, x2.y, s);
    s = fmaf(w[2].z, x2.z, s); s = fmaf(w[2].w, x2.w, s);
    s = fmaf(w[3].x, x3.x, s); s = fmaf(w[3].y, x3.y, s);
    s = fmaf(w[3].z, x3.z, s); s = fmaf(w[3].w, x3.w, s);
    return s;
}

// --------------------------------------------------------------------------
// Coherent (L2-bypassing, L3-served) accessors for cross-block state.
// RELAXED+AGENT => sc0 sc1 load/store, NO cache wb/inv side effects.
// --------------------------------------------------------------------------
__device__ __forceinline__ float2 cload2(const float* p) {
    unsigned long long v = __hip_atomic_load((const unsigned long long*)p,
                                             __ATOMIC_RELAXED, __HIP_MEMORY_SCOPE_AGENT);
    union { unsigned long long u; float2 f; } c; c.u = v; return c.f;
}
__device__ __forceinline__ void cstore2(float* p, float2 v) {
    union { float2 f; unsigned long long u; } c; c.f = v;
    __hip_atomic_store((unsigned long long*)p, c.u,
                       __ATOMIC_RELAXED, __HIP_MEMORY_SCOPE_AGENT);
}
__device__ __forceinline__ float cload(const float* p) {
    unsigned v = __hip_atomic_load((const unsigned*)p,
                                   __ATOMIC_RELAXED, __HIP_MEMORY_SCOPE_AGENT);
    return __uint_as_float(v);
}
__device__ __forceinline__ void cstore(float* p, float v) {
    __hip_atomic_store((unsigned*)p, __float_as_uint(v),
                       __ATOMIC_RELAXED, __HIP_MEMORY_SCOPE_AGENT);
}

// --------------------------------------------------------------------------
// Fence-free grid barrier. flags[bid] (private slot per block, monotonic seq,
// plain relaxed store => no RMW contention, no cache maintenance). Block 0's
// threads aggregate all flags in parallel, then publish gen=seq.
// Release = per-wave s_waitcnt vmcnt(0): all our coherent stores are
// write-through, so drain == globally visible at L3.
// --------------------------------------------------------------------------
__device__ __forceinline__ void gbar(unsigned* flags, unsigned* gen, unsigned seq) {
    asm volatile("s_waitcnt vmcnt(0)" ::: "memory");  // per-wave store drain
    __syncthreads();
    if (blockIdx.x == 0) {
        int i = threadIdx.x;
        if (i >= 1 && i < (int)NB) {
            while (__hip_atomic_load(&flags[i], __ATOMIC_RELAXED,
                                     __HIP_MEMORY_SCOPE_AGENT) < seq)
                __builtin_amdgcn_s_sleep(4);
        }
        __syncthreads();
        if (i == 0)
            __hip_atomic_store(gen, seq, __ATOMIC_RELAXED, __HIP_MEMORY_SCOPE_AGENT);
    } else {
        if (threadIdx.x == 0) {
            __hip_atomic_store(&flags[blockIdx.x], seq,
                               __ATOMIC_RELAXED, __HIP_MEMORY_SCOPE_AGENT);
            while (__hip_atomic_load(gen, __ATOMIC_RELAXED,
                                     __HIP_MEMORY_SCOPE_AGENT) < seq)
                __builtin_amdgcn_s_sleep(4);
        }
        __syncthreads();
    }
    asm volatile("" ::: "memory");
}

// ---------------------------------------------------------------------------
// k_init: mean over P  (+ zero barrier flags).  grid=(8,64), 256 thr.
// ---------------------------------------------------------------------------
__global__ __launch_bounds__(256) void k_init(const float* __restrict__ enc,
                                              float* __restrict__ mean,
                                              unsigned* __restrict__ bar) {
    if (blockIdx.x == 0 && blockIdx.y == 0) {
        bar[threadIdx.x] = 0u;
        if (threadIdx.x == 0) bar[256] = 0u;
    }
    int dc = blockIdx.x, b = blockIdx.y, d = dc * 256 + threadIdx.x;
    const float* base = enc + (size_t)b * P_ * ENC_ + d;
    float s = 0.f;
    for (int p = 0; p < P_; p++) s += base[(size_t)p * ENC_];
    mean[(size_t)b * ENC_ + d] = s / 196.0f;
}

// ---------------------------------------------------------------------------
// k_big: fp32 GEMM, 128x128 tile, BK=16, split 8x8 micro-tile. (unchanged)
// blocks 0..391: att1 = enc @ We^T ; 392..395: h0 -> X h-slot ; 396..399: c0.
// ---------------------------------------------------------------------------
__global__ __launch_bounds__(256) void k_big(
    const float* __restrict__ enc, const float* __restrict__ mean,
    const float* __restrict__ We, const float* __restrict__ be,
    const float* __restrict__ Wh0, const float* __restrict__ bh0,
    const float* __restrict__ Wc0, const float* __restrict__ bc0,
    float* __restrict__ att1, float* __restrict__ X, float* __restrict__ cbuf) {
    __shared__ __align__(16) float As[16][132];
    __shared__ __align__(16) float Ws[16][132];
    int gx = blockIdx.x;
    const float *A, *W, *bias;
    float* C;
    int m0, n0, Mtot, cstr;
    if (gx < 392) {
        A = enc; W = We; bias = be; C = att1;
        m0 = (gx >> 2) * 128; n0 = (gx & 3) * 128; Mtot = 12544; cstr = 512;
    } else if (gx < 396) {
        A = mean; W = Wh0; bias = bh0; C = X + 2560;
        m0 = 0; n0 = (gx - 392) * 128; Mtot = 64; cstr = XSTR;
    } else {
        A = mean; W = Wc0; bias = bc0; C = cbuf;
        m0 = 0; n0 = (gx - 396) * 128; Mtot = 64; cstr = 512;
    }
    int tid = threadIdx.x, tx = tid & 15, ty = tid >> 4;
    int srow = tid >> 2, skq = tid & 3;
    float acc[2][2][4][4] = {};
    int r0 = m0 + min(srow, Mtot - 1);
    int r1 = m0 + min(srow + 64, Mtot - 1);
    const float* a0p = A + (size_t)r0 * 2048 + skq * 4;
    const float* a1p = A + (size_t)r1 * 2048 + skq * 4;
    const float* w0p = W + (size_t)(n0 + srow) * 2048 + skq * 4;
    const float* w1p = W + (size_t)(n0 + srow + 64) * 2048 + skq * 4;
    for (int kk = 0; kk < 2048; kk += 16) {
        float4 a0v = *(const float4*)(a0p + kk);
        float4 a1v = *(const float4*)(a1p + kk);
        float4 w0v = *(const float4*)(w0p + kk);
        float4 w1v = *(const float4*)(w1p + kk);
        __syncthreads();
        As[skq * 4 + 0][srow] = a0v.x; As[skq * 4 + 1][srow] = a0v.y;
        As[skq * 4 + 2][srow] = a0v.z; As[skq * 4 + 3][srow] = a0v.w;
        As[skq * 4 + 0][srow + 64] = a1v.x; As[skq * 4 + 1][srow + 64] = a1v.y;
        As[skq * 4 + 2][srow + 64] = a1v.z; As[skq * 4 + 3][srow + 64] = a1v.w;
        Ws[skq * 4 + 0][srow] = w0v.x; Ws[skq * 4 + 1][srow] = w0v.y;
        Ws[skq * 4 + 2][srow] = w0v.z; Ws[skq * 4 + 3][srow] = w0v.w;
        Ws[skq * 4 + 0][srow + 64] = w1v.x; Ws[skq * 4 + 1][srow + 64] = w1v.y;
        Ws[skq * 4 + 2][srow + 64] = w1v.z; Ws[skq * 4 + 3][srow + 64] = w1v.w;
        __syncthreads();
#pragma unroll
        for (int k = 0; k < 16; k++) {
            float4 av0 = *(const float4*)&As[k][ty * 4];
            float4 av1 = *(const float4*)&As[k][64 + ty * 4];
            float4 bv0 = *(const float4*)&Ws[k][tx * 4];
            float4 bv1 = *(const float4*)&Ws[k][64 + tx * 4];
            float ar[2][4] = {{av0.x, av0.y, av0.z, av0.w}, {av1.x, av1.y, av1.z, av1.w}};
            float br[2][4] = {{bv0.x, bv0.y, bv0.z, bv0.w}, {bv1.x, bv1.y, bv1.z, bv1.w}};
#pragma unroll
            for (int ih = 0; ih < 2; ih++)
#pragma unroll
                for (int jh = 0; jh < 2; jh++)
#pragma unroll
                    for (int i = 0; i < 4; i++)
#pragma unroll
                        for (int j = 0; j < 4; j++)
                            acc[ih][jh][i][j] = fmaf(ar[ih][i], br[jh][j], acc[ih][jh][i][j]);
        }
    }
#pragma unroll
    for (int ih = 0; ih < 2; ih++)
#pragma unroll
        for (int i = 0; i < 4; i++) {
            int m = m0 + ih * 64 + ty * 4 + i;
            if (m - m0 < Mtot) {
#pragma unroll
                for (int jh = 0; jh < 2; jh++) {
                    int n = n0 + jh * 64 + tx * 4;
                    float4 o;
                    o.x = acc[ih][jh][i][0] + bias[n + 0];
                    o.y = acc[ih][jh][i][1] + bias[n + 1];
                    o.z = acc[ih][jh][i][2] + bias[n + 2];
                    o.w = acc[ih][jh][i][3] + bias[n + 3];
                    *(float4*)(C + (size_t)m * cstr + n) = o;
                }
            }
        }
}

// ---------------------------------------------------------------------------
// k_emb0: X emb-slot <- emb[dec_in[:,0]].  grid=64, 256 thr.
// ---------------------------------------------------------------------------
__global__ __launch_bounds__(256) void k_emb0(const float* __restrict__ emb,
                                              const int* __restrict__ dec,
                                              float* __restrict__ X) {
    int b = blockIdx.x, tid = threadIdx.x;
    int tok = dec[b * L_];
    X[(size_t)b * XSTR + 2048 + tid] = emb[(size_t)tok * 512 + tid];
    X[(size_t)b * XSTR + 2048 + 256 + tid] = emb[(size_t)tok * 512 + 256 + tid];
}

// ===========================================================================
// Persistent mega-kernel phases. Grid = 256 blocks x 256 thr (4 waves/block).
// Cross-block data (X, att2buf, pg, out) via coherent ops; weights/enc/att1
// via plain cached loads (stable block->data mapping => L2-resident).
// ===========================================================================

// gates: block bid<8*kcT: kc=bid>>3, 4 waves = 4 consecutive nt. X chunk is
// staged (coherent) into LDS once per sub-chunk, shared by the 4 waves.
__device__ __forceinline__ void ph_gates(int bid, int tid, int wid, int lane,
                                         const float* X, const float* Wih,
                                         const float* Whh, float* pg,
                                         int kcT, int chunk, float* s_stage) {
    bool act = (bid < 8 * kcT);
    int kc = bid >> 3;
    int kbase = kc * chunk;
    int nt = (bid * 4 + wid) & 31;
    int row = nt * 64 + lane;
    const float* wih_row = Wih + (size_t)row * 2560;
    const float* whh_row = Whh + (size_t)row * 512;
    float acc[64];
#pragma unroll
    for (int b = 0; b < 64; b++) acc[b] = 0.f;
    for (int sc = 0; sc < chunk; sc += SUBCH) {
        int cl = min(SUBCH, chunk - sc);
        if (act) {
            int hcl = cl >> 1;
            for (int b = wid * 16; b < wid * 16 + 16; b++) {
                const float* xr = X + (size_t)b * XSTR + kbase + sc;
                float* sr = s_stage + b * SUBCH;
                for (int j2 = lane; j2 < hcl; j2 += 64)
                    *(float2*)&sr[j2 * 2] = cload2(xr + j2 * 2);
            }
        }
        __syncthreads();
        if (act) {
#pragma unroll 1
            for (int k16 = sc; k16 < sc + cl; k16 += 16) {
                int kk = kbase + k16;
                const float* wr = (kk < 2560) ? (wih_row + kk) : (whh_row + (kk - 2560));
                float4 w[4];
                w[0] = *(const float4*)(wr);
                w[1] = *(const float4*)(wr + 4);
                w[2] = *(const float4*)(wr + 8);
                w[3] = *(const float4*)(wr + 12);
                const float* xc = s_stage + (k16 - sc);
#pragma unroll
                for (int b = 0; b < 64; b++)
                    acc[b] += dot16(w, xc + b * SUBCH);
            }
        }
        __syncthreads();
    }
    if (act) {
        float* prow = pg + ((size_t)kc * 64) * 2048 + row;
#pragma unroll
        for (int b = 0; b < 64; b++)
            cstore(prow + (size_t)b * 2048, acc[b]);
    }
}

// lstm: 64 blocks, block=b, thread=j-pair. cbuf is block-private (plain).
__device__ __forceinline__ void ph_lstm(int bid, int tid, const float* pg,
                                        const float* bih, const float* bhh,
                                        float* X, float* cbuf, int kcT) {
    if (bid >= 64) return;
    int b = bid, j = tid * 2;
    float2 g[4];
#pragma unroll
    for (int gi = 0; gi < 4; gi++) {
        int n = gi * 512 + j;
        float2 s = make_float2(bih[n] + bhh[n], bih[n + 1] + bhh[n + 1]);
#pragma unroll 4
        for (int kc = 0; kc < kcT; kc++) {
            float2 p = cload2(pg + ((size_t)kc * 64 + b) * 2048 + n);
            s.x += p.x; s.y += p.y;
        }
        g[gi] = s;
    }
    float2 c = *(float2*)(cbuf + b * 512 + j);
    float2 cn, hn;
    cn.x = sigmf(g[1].x) * c.x + sigmf(g[0].x) * tanhf(g[2].x);
    cn.y = sigmf(g[1].y) * c.y + sigmf(g[0].y) * tanhf(g[2].y);
    hn.x = sigmf(g[3].x) * tanhf(cn.x);
    hn.y = sigmf(g[3].y) * tanhf(cn.y);
    *(float2*)(cbuf + b * 512 + j) = cn;
    cstore2(X + (size_t)b * XSTR + 2560 + j, hn);
}

// stage h (all 64 b, 128KB) coherently into LDS. Called by ALL blocks.
__device__ __forceinline__ void ph_hstage(bool act, int wid, int lane,
                                          const float* X, float* s_stage) {
    if (act) {
        for (int b = wid * 16; b < wid * 16 + 16; b++) {
            const float* xr = X + (size_t)b * XSTR + 2560;
            float* sr = s_stage + b * 512;
            for (int j2 = lane; j2 < 256; j2 += 64)
                *(float2*)&sr[j2 * 2] = cload2(xr + j2 * 2);
        }
    }
    __syncthreads();
}

// logits: blocks 0..156 (nt=bid, bg=wid). h from LDS. out stores coherent.
__device__ __forceinline__ void ph_logits(int bid, int wid, int lane,
                                          const float* s_stage, const float* Wv,
                                          const float* bv, float* out, int t) {
    int v = bid * 64 + lane;
    int vr = min(v, V_ - 1);
    const float* wrow = Wv + (size_t)vr * 512;
    const float* xbase = s_stage + wid * 16 * 512;
    float acc[16];
#pragma unroll
    for (int b = 0; b < 16; b++) acc[b] = 0.f;
#pragma unroll 1
    for (int k16 = 0; k16 < 512; k16 += 16) {
        float4 w[4];
        w[0] = *(const float4*)(wrow + k16);
        w[1] = *(const float4*)(wrow + k16 + 4);
        w[2] = *(const float4*)(wrow + k16 + 8);
        w[3] = *(const float4*)(wrow + k16 + 12);
        const float* xc = xbase + k16;
#pragma unroll
        for (int b = 0; b < 16; b++)
            acc[b] += dot16(w, xc + b * 512);
    }
    if (v < V_) {
        float bias = bv[v];
#pragma unroll
        for (int b = 0; b < 16; b++) {
            int bb = wid * 16 + b;
            cstore(out + ((size_t)bb * L_ + t) * V_ + v, acc[b] + bias);
        }
    }
}

// att2: blocks 157..172 (64 wave-tasks). h from LDS. stores coherent.
__device__ __forceinline__ void ph_att2c(int bid, int wid, int lane,
                                         const float* s_stage, const float* Wd,
                                         const float* bd, float* att2buf) {
    int task = (bid - 157) * 4 + wid;  // [0,64)
    int nt = task >> 3, bg = task & 7;
    int n = nt * 64 + lane;
    const float* wrow = Wd + (size_t)n * 512;
    const float* xbase = s_stage + bg * 8 * 512;
    float acc[8];
#pragma unroll
    for (int b = 0; b < 8; b++) acc[b] = 0.f;
#pragma unroll 1
    for (int k16 = 0; k16 < 512; k16 += 16) {
        float4 w[4];
        w[0] = *(const float4*)(wrow + k16);
        w[1] = *(const float4*)(wrow + k16 + 4);
        w[2] = *(const float4*)(wrow + k16 + 8);
        w[3] = *(const float4*)(wrow + k16 + 12);
        const float* xc = xbase + k16;
#pragma unroll
        for (int b = 0; b < 8; b++)
            acc[b] += dot16(w, xc + b * 512);
    }
    float bias = bd[n];
#pragma unroll
    for (int b = 0; b < 8; b++)
        cstore(att2buf + (size_t)(bg * 8 + b) * 512 + n, acc[b] + bias);
}

// fin: blocks 0..15, wave = one b. argmax(out) coherent; emb -> X coherent.
__device__ __forceinline__ void ph_fin(int bid, int wid, int lane,
                                       const float* out, const float* emb,
                                       float* X, int t) {
    int b = bid * 4 + wid;
    const float* orow = out + ((size_t)b * L_ + t) * V_;
    float best = -INFINITY;
    int bi = 0;
#pragma unroll 4
    for (int v = lane; v < V_; v += 64) {
        float s = cload(orow + v);
        if (s > best) { best = s; bi = v; }
    }
#pragma unroll
    for (int m = 32; m >= 1; m >>= 1) {
        float ob = __shfl_xor(best, m, 64);
        int oi = __shfl_xor(bi, m, 64);
        if (ob > best || (ob == best && oi < bi)) { best = ob; bi = oi; }
    }
    const float4* e4 = (const float4*)(emb + (size_t)bi * 512);
    float4 v0 = e4[lane], v1 = e4[lane + 64];
    float* xp = X + (size_t)b * XSTR + 2048;
    cstore2(xp + lane * 4,       make_float2(v0.x, v0.y));
    cstore2(xp + lane * 4 + 2,   make_float2(v0.z, v0.w));
    cstore2(xp + 256 + lane * 4,     make_float2(v1.x, v1.y));
    cstore2(xp + 256 + lane * 4 + 2, make_float2(v1.z, v1.w));
}

// e + softmax + ctx, fused per block. ALL 256 blocks: b=bid>>2, dc=bid&3.
// att2 staged coherently; att1/enc plain cached; ctx written coherent.
__device__ __forceinline__ void ph_ctx(int bid, int tid, int wid, int lane,
                                       const float* enc, const float* att1,
                                       const float* att2buf, const float* Wf,
                                       const float* bfp, float* atts_out,
                                       float* X, int t, float* s_att2,
                                       float* s_e, float* s_red, float* s_att) {
    int b = bid >> 2, dc = bid & 3;
    *(float2*)&s_att2[tid * 2] = cload2(att2buf + (size_t)b * 512 + tid * 2);
    __syncthreads();
    const float4* a24 = (const float4*)s_att2;
    float4 t0 = a24[lane], t1 = a24[lane + 64];
    const float4* wf4 = (const float4*)Wf;
    float4 f0 = wf4[lane], f1 = wf4[lane + 64];
    float bfv = bfp[0];
    for (int p = wid; p < P_; p += 4) {
        const float4* rr = (const float4*)(att1 + ((size_t)b * P_ + p) * 512);
        float4 v0 = rr[lane], v1 = rr[lane + 64];
        float s = fmaxf(v0.x + t0.x, 0.f) * f0.x + fmaxf(v0.y + t0.y, 0.f) * f0.y +
                  fmaxf(v0.z + t0.z, 0.f) * f0.z + fmaxf(v0.w + t0.w, 0.f) * f0.w +
                  fmaxf(v1.x + t1.x, 0.f) * f1.x + fmaxf(v1.y + t1.y, 0.f) * f1.y +
                  fmaxf(v1.z + t1.z, 0.f) * f1.z + fmaxf(v1.w + t1.w, 0.f) * f1.w;
        s = wred_sum(s);
        if (lane == 0) s_e[p] = s + bfv;
    }
    __syncthreads();
    float val = (tid < P_) ? s_e[tid] : -INFINITY;
    s_red[tid] = val;
    __syncthreads();
    for (int s = 128; s > 0; s >>= 1) {
        if (tid < s) s_red[tid] = fmaxf(s_red[tid], s_red[tid + s]);
        __syncthreads();
    }
    float m = s_red[0];
    __syncthreads();
    float ex = (tid < P_) ? expf(val - m) : 0.f;
    s_red[tid] = ex;
    __syncthreads();
    for (int s = 128; s > 0; s >>= 1) {
        if (tid < s) s_red[tid] += s_red[tid + s];
        __syncthreads();
    }
    float sum = s_red[0];
    if (tid < P_) {
        float att = ex / sum;
        s_att[tid] = att;
        if (dc == 0) atts_out[((size_t)b * L_ + t) * P_ + tid] = att;
    }
    __syncthreads();
    int d = dc * 512 + tid * 2;
    const float* base = enc + (size_t)b * P_ * ENC_ + d;
    float a0 = 0, a1 = 0, a2 = 0, a3 = 0;
    float c0 = 0, c1 = 0, c2 = 0, c3 = 0;
#pragma unroll 1
    for (int p = 0; p < P_; p += 4) {
        float w0 = s_att[p + 0], w1 = s_att[p + 1];
        float w2 = s_att[p + 2], w3 = s_att[p + 3];
        float2 v0 = *(const float2*)(base + (size_t)(p + 0) * ENC_);
        float2 v1 = *(const float2*)(base + (size_t)(p + 1) * ENC_);
        float2 v2 = *(const float2*)(base + (size_t)(p + 2) * ENC_);
        float2 v3 = *(const float2*)(base + (size_t)(p + 3) * ENC_);
        a0 = fmaf(w0, v0.x, a0); c0 = fmaf(w0, v0.y, c0);
        a1 = fmaf(w1, v1.x, a1); c1 = fmaf(w1, v1.y, c1);
        a2 = fmaf(w2, v2.x, a2); c2 = fmaf(w2, v2.y, c2);
        a3 = fmaf(w3, v3.x, a3); c3 = fmaf(w3, v3.y, c3);
    }
    float2 o;
    o.x = (a0 + a1) + (a2 + a3);
    o.y = (c0 + c1) + (c2 + c3);
    cstore2(X + (size_t)b * XSTR + d, o);
}

// ---------------------------------------------------------------------------
// k_mega: 30-step decode loop, persistent, 4 grid barriers/step.
// ---------------------------------------------------------------------------
__global__ __launch_bounds__(256) void k_mega(
    const float* __restrict__ enc, const float* __restrict__ emb,
    const float* __restrict__ Wd, const float* __restrict__ bd,
    const float* __restrict__ Wf, const float* __restrict__ bfp,
    const float* __restrict__ Wih, const float* __restrict__ bih,
    const float* __restrict__ Whh, const float* __restrict__ bhh,
    const float* __restrict__ Wv, const float* __restrict__ bv,
    const float* __restrict__ att1, float* __restrict__ X,
    float* __restrict__ cbuf, float* __restrict__ att2buf,
    float* __restrict__ pg, float* __restrict__ out,
    float* __restrict__ atts_out, unsigned* __restrict__ bar,
    int kcT, int chunk) {
    const int bid = blockIdx.x, tid = threadIdx.x;
    const int wid = tid >> 6, lane = tid & 63;
    __shared__ __align__(16) float s_stage[64 * SUBCH];  // 128 KiB
    __shared__ __align__(16) float s_att2[512];
    __shared__ float s_e[256];
    __shared__ float s_red[256];
    __shared__ float s_att[256];
    unsigned* flags = bar;
    unsigned* gen = bar + 256;
    unsigned seq = 1;

    // prologue: att2_0 -> {e,softmax,ctx}_0
    ph_hstage(bid >= 157 && bid < 173, wid, lane, X, s_stage);
    if (bid >= 157 && bid < 173) ph_att2c(bid, wid, lane, s_stage, Wd, bd, att2buf);
    gbar(flags, gen, seq); seq++;
    ph_ctx(bid, tid, wid, lane, enc, att1, att2buf, Wf, bfp, atts_out, X, 0,
           s_att2, s_e, s_red, s_att);
    gbar(flags, gen, seq); seq++;

#pragma unroll 1
    for (int t = 0; t < L_; ++t) {
        ph_gates(bid, tid, wid, lane, X, Wih, Whh, pg, kcT, chunk, s_stage);
        gbar(flags, gen, seq); seq++;
        ph_lstm(bid, tid, pg, bih, bhh, X, cbuf, kcT);
        gbar(flags, gen, seq); seq++;
        ph_hstage(bid < 173, wid, lane, X, s_stage);
        if (bid < 157) ph_logits(bid, wid, lane, s_stage, Wv, bv, out, t);
        else if (bid < 173) ph_att2c(bid, wid, lane, s_stage, Wd, bd, att2buf);
        gbar(flags, gen, seq); seq++;
        if (t == L_ - 1) break;
        if (bid < 16) ph_fin(bid, wid, lane, out, emb, X, t);
        ph_ctx(bid, tid, wid, lane, enc, att1, att2buf, Wf, bfp, atts_out, X,
               t + 1, s_att2, s_e, s_red, s_att);
        gbar(flags, gen, seq); seq++;
    }
}

// ---------------------------------------------------------------------------
extern "C" void kernel_launch(void* const* d_in, const int* in_sizes, int n_in,
                              void* d_out, int out_size, void* d_ws, size_t ws_size,
                              hipStream_t stream) {
    const float* enc = (const float*)d_in[0];
    const int* dec   = (const int*)d_in[1];
    const float* emb = (const float*)d_in[3];
    const float* We  = (const float*)d_in[4];
    const float* be  = (const float*)d_in[5];
    const float* Wd  = (const float*)d_in[6];
    const float* bd  = (const float*)d_in[7];
    const float* Wf  = (const float*)d_in[8];
    const float* bf  = (const float*)d_in[9];
    const float* Wih = (const float*)d_in[10];
    const float* bih = (const float*)d_in[11];
    const float* Whh = (const float*)d_in[12];
    const float* bhh = (const float*)d_in[13];
    const float* Wh0 = (const float*)d_in[14];
    const float* bh0 = (const float*)d_in[15];
    const float* Wc0 = (const float*)d_in[16];
    const float* bc0 = (const float*)d_in[17];
    const float* Wv  = (const float*)d_in[18];
    const float* bv  = (const float*)d_in[19];

    float* out = (float*)d_out;
    float* ws = (float*)d_ws;

    // workspace layout (floats)
    float* att1    = ws;                   // 6,422,528
    float* X       = att1 + 6422528;       //   196,608
    float* cbuf    = X + 196608;           //    32,768
    float* att2buf = cbuf + 32768;         //    32,768
    unsigned* bar  = (unsigned*)(att2buf + 32768);  // 512-float slot (257 used)
    float* pg      = ws + 6685184;         // kcT * 131,072 gate partials
    float* mean    = pg;                   // alias: only live before k_mega

    const size_t base_fl = 6685184;
    size_t avail_fl = ws_size / 4;
    int kcT = 2, chunk = 1536;
    const int opt_kc[5] = {32, 16, 8, 4, 2};
    for (int i = 0; i < 5; i++) {
        if (avail_fl >= base_fl + (size_t)opt_kc[i] * 131072) {
            kcT = opt_kc[i];
            chunk = 3072 / kcT;
            break;
        }
    }

    float* atts_out = out + (size_t)B_ * L_ * V_;

    hipLaunchKernelGGL(k_init, dim3(8, 64), dim3(256), 0, stream, enc, mean, bar);
    hipLaunchKernelGGL(k_big, dim3(400), dim3(256), 0, stream, enc, mean, We, be,
                       Wh0, bh0, Wc0, bc0, att1, X, cbuf);
    hipLaunchKernelGGL(k_emb0, dim3(64), dim3(256), 0, stream, emb, dec, X);
    hipLaunchKernelGGL(k_mega, dim3(NB), dim3(256), 0, stream,
                       enc, emb, Wd, bd, Wf, bf, Wih, bih, Whh, bhh, Wv, bv,
                       att1, X, cbuf, att2buf, pg, out, atts_out, bar,
                       kcT, chunk);
}

// Round 3
// 7144.922 us; speedup vs baseline: 1.6863x; 1.0122x over previous
//
#include <hip/hip_runtime.h>
#include <math.h>

constexpr int B_   = 64;
constexpr int L_   = 30;
constexpr int P_   = 196;
constexpr int ENC_ = 2048;
constexpr int V_   = 10000;
constexpr int XSTR = 3072;   // X row: [ctx 2048 | emb 512 | h 512]
constexpr unsigned NB = 256; // persistent grid size (1 block/CU)
constexpr int SUBCH = 512;   // gates staging sub-chunk (floats)

__device__ __forceinline__ float sigmf(float x) { return 1.0f / (1.0f + expf(-x)); }

// 16-term dot: w[4] (registers) . x[16] (pointer, 16B-aligned; global or LDS)
__device__ __forceinline__ float dot16(const float4* w, const float* xp) {
    const float4* x4 = (const float4*)xp;
    float4 x0 = x4[0], x1 = x4[1], x2 = x4[2], x3 = x4[3];
    float s = w[0].x * x0.x;
    s = fmaf(w[0].y, x0.y, s); s = fmaf(w[0].z, x0.z, s); s = fmaf(w[0].w, x0.w, s);
    s = fmaf(w[1].x, x1.x, s); s = fmaf(w[1].y, x1.y, s);
    s = fmaf(w[1].z, x1.z, s); s = fmaf(w[1].w, x1.w, s);
    s = fmaf(w[2].x, x2.x, s); s = fmaf(w[2].y, x2.y, s);
    s = fmaf(w[2].z, x2.z, s); s = fmaf(w[2].w, x2.w, s);
    s = fmaf(w[3].x, x3.x, s); s = fmaf(w[3].y, x3.y, s);
    s = fmaf(w[3].z, x3.z, s); s = fmaf(w[3].w, x3.w, s);
    return s;
}

// --------------------------------------------------------------------------
// Coherent (L2-bypassing) accessors for cross-block state.
// --------------------------------------------------------------------------
__device__ __forceinline__ float2 cload2(const float* p) {
    unsigned long long v = __hip_atomic_load((const unsigned long long*)p,
                                             __ATOMIC_RELAXED, __HIP_MEMORY_SCOPE_AGENT);
    union { unsigned long long u; float2 f; } c; c.u = v; return c.f;
}
__device__ __forceinline__ void cstore2(float* p, float2 v) {
    union { float2 f; unsigned long long u; } c; c.f = v;
    __hip_atomic_store((unsigned long long*)p, c.u,
                       __ATOMIC_RELAXED, __HIP_MEMORY_SCOPE_AGENT);
}
__device__ __forceinline__ float cload(const float* p) {
    unsigned v = __hip_atomic_load((const unsigned*)p,
                                   __ATOMIC_RELAXED, __HIP_MEMORY_SCOPE_AGENT);
    return __uint_as_float(v);
}
__device__ __forceinline__ void cstore(float* p, float v) {
    __hip_atomic_store((unsigned*)p, __float_as_uint(v),
                       __ATOMIC_RELAXED, __HIP_MEMORY_SCOPE_AGENT);
}
// non-temporal 8B load (no L2 allocate) for streaming enc reads
__device__ __forceinline__ float2 ntload2(const float* p) {
    union { unsigned long long u; float2 f; } c;
    c.u = __builtin_nontemporal_load((const unsigned long long*)p);
    return c.f;
}

// --------------------------------------------------------------------------
// Fence-free grid barrier (proven in round 2).
// --------------------------------------------------------------------------
__device__ __forceinline__ void gbar(unsigned* flags, unsigned* gen, unsigned seq) {
    asm volatile("s_waitcnt vmcnt(0)" ::: "memory");
    __syncthreads();
    if (blockIdx.x == 0) {
        int i = threadIdx.x;
        if (i >= 1 && i < (int)NB) {
            while (__hip_atomic_load(&flags[i], __ATOMIC_RELAXED,
                                     __HIP_MEMORY_SCOPE_AGENT) < seq)
                __builtin_amdgcn_s_sleep(4);
        }
        __syncthreads();
        if (i == 0)
            __hip_atomic_store(gen, seq, __ATOMIC_RELAXED, __HIP_MEMORY_SCOPE_AGENT);
    } else {
        if (threadIdx.x == 0) {
            __hip_atomic_store(&flags[blockIdx.x], seq,
                               __ATOMIC_RELAXED, __HIP_MEMORY_SCOPE_AGENT);
            while (__hip_atomic_load(gen, __ATOMIC_RELAXED,
                                     __HIP_MEMORY_SCOPE_AGENT) < seq)
                __builtin_amdgcn_s_sleep(4);
        }
        __syncthreads();
    }
    asm volatile("" ::: "memory");
}

// ---------------------------------------------------------------------------
// k_init: mean over P  (+ zero barrier flags).  grid=(8,64), 256 thr.
// ---------------------------------------------------------------------------
__global__ __launch_bounds__(256) void k_init(const float* __restrict__ enc,
                                              float* __restrict__ mean,
                                              unsigned* __restrict__ bar) {
    if (blockIdx.x == 0 && blockIdx.y == 0) {
        bar[threadIdx.x] = 0u;
        if (threadIdx.x == 0) bar[256] = 0u;
    }
    int dc = blockIdx.x, b = blockIdx.y, d = dc * 256 + threadIdx.x;
    const float* base = enc + (size_t)b * P_ * ENC_ + d;
    float s = 0.f;
    for (int p = 0; p < P_; p++) s += base[(size_t)p * ENC_];
    mean[(size_t)b * ENC_ + d] = s / 196.0f;
}

// ---------------------------------------------------------------------------
// k_big: fp32 GEMM, 128x128 tile, BK=16, split 8x8 micro-tile. (unchanged)
// ---------------------------------------------------------------------------
__global__ __launch_bounds__(256) void k_big(
    const float* __restrict__ enc, const float* __restrict__ mean,
    const float* __restrict__ We, const float* __restrict__ be,
    const float* __restrict__ Wh0, const float* __restrict__ bh0,
    const float* __restrict__ Wc0, const float* __restrict__ bc0,
    float* __restrict__ att1, float* __restrict__ X, float* __restrict__ cbuf) {
    __shared__ __align__(16) float As[16][132];
    __shared__ __align__(16) float Ws[16][132];
    int gx = blockIdx.x;
    const float *A, *W, *bias;
    float* C;
    int m0, n0, Mtot, cstr;
    if (gx < 392) {
        A = enc; W = We; bias = be; C = att1;
        m0 = (gx >> 2) * 128; n0 = (gx & 3) * 128; Mtot = 12544; cstr = 512;
    } else if (gx < 396) {
        A = mean; W = Wh0; bias = bh0; C = X + 2560;
        m0 = 0; n0 = (gx - 392) * 128; Mtot = 64; cstr = XSTR;
    } else {
        A = mean; W = Wc0; bias = bc0; C = cbuf;
        m0 = 0; n0 = (gx - 396) * 128; Mtot = 64; cstr = 512;
    }
    int tid = threadIdx.x, tx = tid & 15, ty = tid >> 4;
    int srow = tid >> 2, skq = tid & 3;
    float acc[2][2][4][4] = {};
    int r0 = m0 + min(srow, Mtot - 1);
    int r1 = m0 + min(srow + 64, Mtot - 1);
    const float* a0p = A + (size_t)r0 * 2048 + skq * 4;
    const float* a1p = A + (size_t)r1 * 2048 + skq * 4;
    const float* w0p = W + (size_t)(n0 + srow) * 2048 + skq * 4;
    const float* w1p = W + (size_t)(n0 + srow + 64) * 2048 + skq * 4;
    for (int kk = 0; kk < 2048; kk += 16) {
        float4 a0v = *(const float4*)(a0p + kk);
        float4 a1v = *(const float4*)(a1p + kk);
        float4 w0v = *(const float4*)(w0p + kk);
        float4 w1v = *(const float4*)(w1p + kk);
        __syncthreads();
        As[skq * 4 + 0][srow] = a0v.x; As[skq * 4 + 1][srow] = a0v.y;
        As[skq * 4 + 2][srow] = a0v.z; As[skq * 4 + 3][srow] = a0v.w;
        As[skq * 4 + 0][srow + 64] = a1v.x; As[skq * 4 + 1][srow + 64] = a1v.y;
        As[skq * 4 + 2][srow + 64] = a1v.z; As[skq * 4 + 3][srow + 64] = a1v.w;
        Ws[skq * 4 + 0][srow] = w0v.x; Ws[skq * 4 + 1][srow] = w0v.y;
        Ws[skq * 4 + 2][srow] = w0v.z; Ws[skq * 4 + 3][srow] = w0v.w;
        Ws[skq * 4 + 0][srow + 64] = w1v.x; Ws[skq * 4 + 1][srow + 64] = w1v.y;
        Ws[skq * 4 + 2][srow + 64] = w1v.z; Ws[skq * 4 + 3][srow + 64] = w1v.w;
        __syncthreads();
#pragma unroll
        for (int k = 0; k < 16; k++) {
            float4 av0 = *(const float4*)&As[k][ty * 4];
            float4 av1 = *(const float4*)&As[k][64 + ty * 4];
            float4 bv0 = *(const float4*)&Ws[k][tx * 4];
            float4 bv1 = *(const float4*)&Ws[k][64 + tx * 4];
            float ar[2][4] = {{av0.x, av0.y, av0.z, av0.w}, {av1.x, av1.y, av1.z, av1.w}};
            float br[2][4] = {{bv0.x, bv0.y, bv0.z, bv0.w}, {bv1.x, bv1.y, bv1.z, bv1.w}};
#pragma unroll
            for (int ih = 0; ih < 2; ih++)
#pragma unroll
                for (int jh = 0; jh < 2; jh++)
#pragma unroll
                    for (int i = 0; i < 4; i++)
#pragma unroll
                        for (int j = 0; j < 4; j++)
                            acc[ih][jh][i][j] = fmaf(ar[ih][i], br[jh][j], acc[ih][jh][i][j]);
        }
    }
#pragma unroll
    for (int ih = 0; ih < 2; ih++)
#pragma unroll
        for (int i = 0; i < 4; i++) {
            int m = m0 + ih * 64 + ty * 4 + i;
            if (m - m0 < Mtot) {
#pragma unroll
                for (int jh = 0; jh < 2; jh++) {
                    int n = n0 + jh * 64 + tx * 4;
                    float4 o;
                    o.x = acc[ih][jh][i][0] + bias[n + 0];
                    o.y = acc[ih][jh][i][1] + bias[n + 1];
                    o.z = acc[ih][jh][i][2] + bias[n + 2];
                    o.w = acc[ih][jh][i][3] + bias[n + 3];
                    *(float4*)(C + (size_t)m * cstr + n) = o;
                }
            }
        }
}

// ---------------------------------------------------------------------------
// k_emb0: X emb-slot <- emb[dec_in[:,0]].  grid=64, 256 thr.
// ---------------------------------------------------------------------------
__global__ __launch_bounds__(256) void k_emb0(const float* __restrict__ emb,
                                              const int* __restrict__ dec,
                                              float* __restrict__ X) {
    int b = blockIdx.x, tid = threadIdx.x;
    int tok = dec[b * L_];
    X[(size_t)b * XSTR + 2048 + tid] = emb[(size_t)tok * 512 + tid];
    X[(size_t)b * XSTR + 2048 + 256 + tid] = emb[(size_t)tok * 512 + 256 + tid];
}

// ===========================================================================
// Persistent mega-kernel phases. Grid = 256 blocks x 256 thr (4 waves/block).
// ===========================================================================

// gates: blocks 0..8*kcT-1. X chunk staged (coherent) into LDS, shared.
__device__ __forceinline__ void ph_gates(int bid, int tid, int wid, int lane,
                                         const float* X, const float* Wih,
                                         const float* Whh, float* pg,
                                         int kcT, int chunk, float* s_stage) {
    bool act = (bid < 8 * kcT);
    int kc = bid >> 3;
    int kbase = kc * chunk;
    int nt = (bid * 4 + wid) & 31;
    int row = nt * 64 + lane;
    const float* wih_row = Wih + (size_t)row * 2560;
    const float* whh_row = Whh + (size_t)row * 512;
    float acc[64];
#pragma unroll
    for (int b = 0; b < 64; b++) acc[b] = 0.f;
    for (int sc = 0; sc < chunk; sc += SUBCH) {
        int cl = min(SUBCH, chunk - sc);
        if (act) {
            int hcl = cl >> 1;
            for (int b = wid * 16; b < wid * 16 + 16; b++) {
                const float* xr = X + (size_t)b * XSTR + kbase + sc;
                float* sr = s_stage + b * SUBCH;
                for (int j2 = lane; j2 < hcl; j2 += 64)
                    *(float2*)&sr[j2 * 2] = cload2(xr + j2 * 2);
            }
        }
        __syncthreads();
        if (act) {
#pragma unroll 1
            for (int k16 = sc; k16 < sc + cl; k16 += 16) {
                int kk = kbase + k16;
                const float* wr = (kk < 2560) ? (wih_row + kk) : (whh_row + (kk - 2560));
                float4 w[4];
                w[0] = *(const float4*)(wr);
                w[1] = *(const float4*)(wr + 4);
                w[2] = *(const float4*)(wr + 8);
                w[3] = *(const float4*)(wr + 12);
                const float* xc = s_stage + (k16 - sc);
#pragma unroll
                for (int b = 0; b < 64; b++)
                    acc[b] += dot16(w, xc + b * SUBCH);
            }
        }
        __syncthreads();
    }
    if (act) {
        float* prow = pg + ((size_t)kc * 64) * 2048 + row;
#pragma unroll
        for (int b = 0; b < 64; b++)
            cstore(prow + (size_t)b * 2048, acc[b]);
    }
}

// lstm: 64 blocks, block=b. cbuf block-private (plain, stable CU mapping).
__device__ __forceinline__ void ph_lstm(int bid, int tid, const float* pg,
                                        const float* bih, const float* bhh,
                                        float* X, float* cbuf, int kcT) {
    if (bid >= 64) return;
    int b = bid, j = tid * 2;
    float2 g[4];
#pragma unroll
    for (int gi = 0; gi < 4; gi++) {
        int n = gi * 512 + j;
        float2 s = make_float2(bih[n] + bhh[n], bih[n + 1] + bhh[n + 1]);
#pragma unroll 4
        for (int kc = 0; kc < kcT; kc++) {
            float2 p = cload2(pg + ((size_t)kc * 64 + b) * 2048 + n);
            s.x += p.x; s.y += p.y;
        }
        g[gi] = s;
    }
    float2 c = *(float2*)(cbuf + b * 512 + j);
    float2 cn, hn;
    cn.x = sigmf(g[1].x) * c.x + sigmf(g[0].x) * tanhf(g[2].x);
    cn.y = sigmf(g[1].y) * c.y + sigmf(g[0].y) * tanhf(g[2].y);
    hn.x = sigmf(g[3].x) * tanhf(cn.x);
    hn.y = sigmf(g[3].y) * tanhf(cn.y);
    *(float2*)(cbuf + b * 512 + j) = cn;
    cstore2(X + (size_t)b * XSTR + 2560 + j, hn);
}

// stage h (all 64 b, 128KB) coherently into LDS.
__device__ __forceinline__ void ph_hstage(bool act, int wid, int lane,
                                          const float* X, float* s_stage) {
    if (act) {
        for (int b = wid * 16; b < wid * 16 + 16; b++) {
            const float* xr = X + (size_t)b * XSTR + 2560;
            float* sr = s_stage + b * 512;
            for (int j2 = lane; j2 < 256; j2 += 64)
                *(float2*)&sr[j2 * 2] = cload2(xr + j2 * 2);
        }
    }
    __syncthreads();
}

// logits: blocks 0..156. h from LDS. out + per-(b,segment) argmax partials.
__device__ __forceinline__ void ph_logits(int bid, int wid, int lane,
                                          const float* s_stage, const float* Wv,
                                          const float* bv, float* out,
                                          float* pargmax, int t) {
    int v = bid * 64 + lane;
    int vr = min(v, V_ - 1);
    const float* wrow = Wv + (size_t)vr * 512;
    const float* xbase = s_stage + wid * 16 * 512;
    float acc[16];
#pragma unroll
    for (int b = 0; b < 16; b++) acc[b] = 0.f;
#pragma unroll 1
    for (int k16 = 0; k16 < 512; k16 += 16) {
        float4 w[4];
        w[0] = *(const float4*)(wrow + k16);
        w[1] = *(const float4*)(wrow + k16 + 4);
        w[2] = *(const float4*)(wrow + k16 + 8);
        w[3] = *(const float4*)(wrow + k16 + 12);
        const float* xc = xbase + k16;
#pragma unroll
        for (int b = 0; b < 16; b++)
            acc[b] += dot16(w, xc + b * 512);
    }
    float bias = bv[vr];
#pragma unroll
    for (int b = 0; b < 16; b++) {
        float val = acc[b] + bias;
        int bb = wid * 16 + b;
        if (v < V_) cstore(out + ((size_t)bb * L_ + t) * V_ + v, val);
        float mval = (v < V_) ? val : -INFINITY;
        int midx = v;
#pragma unroll
        for (int m = 32; m >= 1; m >>= 1) {
            float ov = __shfl_xor(mval, m, 64);
            int oi = __shfl_xor(midx, m, 64);
            if (ov > mval || (ov == mval && oi < midx)) { mval = ov; midx = oi; }
        }
        if (lane == 0)
            cstore2(pargmax + ((size_t)bb * 157 + bid) * 2,
                    make_float2(mval, (float)midx));
    }
}

// att2: blocks 157..172 (64 wave-tasks). h from LDS. stores coherent.
__device__ __forceinline__ void ph_att2c(int bid, int wid, int lane,
                                         const float* s_stage, const float* Wd,
                                         const float* bd, float* att2buf) {
    int task = (bid - 157) * 4 + wid;  // [0,64)
    int nt = task >> 3, bg = task & 7;
    int n = nt * 64 + lane;
    const float* wrow = Wd + (size_t)n * 512;
    const float* xbase = s_stage + bg * 8 * 512;
    float acc[8];
#pragma unroll
    for (int b = 0; b < 8; b++) acc[b] = 0.f;
#pragma unroll 1
    for (int k16 = 0; k16 < 512; k16 += 16) {
        float4 w[4];
        w[0] = *(const float4*)(wrow + k16);
        w[1] = *(const float4*)(wrow + k16 + 4);
        w[2] = *(const float4*)(wrow + k16 + 8);
        w[3] = *(const float4*)(wrow + k16 + 12);
        const float* xc = xbase + k16;
#pragma unroll
        for (int b = 0; b < 8; b++)
            acc[b] += dot16(w, xc + b * 512);
    }
    float bias = bd[n];
#pragma unroll
    for (int b = 0; b < 8; b++)
        cstore(att2buf + (size_t)(bg * 8 + b) * 512 + n, acc[b] + bias);
}

// e + softmax for ONE b per block (blocks 0..63). att1 plain (L2-stable),
// att2 coherent. Writes attbuf (coherent) + atts_out (plain, own L2).
__device__ __forceinline__ void ph_e(int bid, int tid, int wid, int lane,
                                     const float* att1, const float* att2buf,
                                     const float* Wf, const float* bfp,
                                     float* attbuf, float* atts_out, int t,
                                     float* s_att2, float* s_e, float* s_red) {
    int b = bid;
    *(float2*)&s_att2[tid * 2] = cload2(att2buf + (size_t)b * 512 + tid * 2);
    __syncthreads();
    const float4* a24 = (const float4*)s_att2;
    float4 t0 = a24[lane], t1 = a24[lane + 64];
    const float4* wf4 = (const float4*)Wf;
    float4 f0 = wf4[lane], f1 = wf4[lane + 64];
    float bfv = bfp[0];
    for (int p = wid; p < P_; p += 4) {
        const float4* rr = (const float4*)(att1 + ((size_t)b * P_ + p) * 512);
        float4 v0 = rr[lane], v1 = rr[lane + 64];
        float s = fmaxf(v0.x + t0.x, 0.f) * f0.x + fmaxf(v0.y + t0.y, 0.f) * f0.y +
                  fmaxf(v0.z + t0.z, 0.f) * f0.z + fmaxf(v0.w + t0.w, 0.f) * f0.w +
                  fmaxf(v1.x + t1.x, 0.f) * f1.x + fmaxf(v1.y + t1.y, 0.f) * f1.y +
                  fmaxf(v1.z + t1.z, 0.f) * f1.z + fmaxf(v1.w + t1.w, 0.f) * f1.w;
#pragma unroll
        for (int m = 32; m >= 1; m >>= 1) s += __shfl_xor(s, m, 64);
        if (lane == 0) s_e[p] = s + bfv;
    }
    __syncthreads();
    float val = (tid < P_) ? s_e[tid] : -INFINITY;
    s_red[tid] = val;
    __syncthreads();
    for (int s = 128; s > 0; s >>= 1) {
        if (tid < s) s_red[tid] = fmaxf(s_red[tid], s_red[tid + s]);
        __syncthreads();
    }
    float m = s_red[0];
    __syncthreads();
    float ex = (tid < P_) ? expf(val - m) : 0.f;
    s_red[tid] = ex;
    __syncthreads();
    for (int s = 128; s > 0; s >>= 1) {
        if (tid < s) s_red[tid] += s_red[tid + s];
        __syncthreads();
    }
    float sum = s_red[0];
    if (tid < P_) {
        float att = ex / sum;
        cstore(attbuf + b * 256 + tid, att);
        atts_out[((size_t)b * L_ + t) * P_ + tid] = att;
    }
}

// fin: blocks 200..215, wave = one b. Reduce 157 argmax partials; emb -> X.
__device__ __forceinline__ void ph_fin(int bid, int wid, int lane,
                                       const float* pargmax, const float* emb,
                                       float* X) {
    int b = (bid - 200) * 4 + wid;
    float best = -INFINITY;
    int bi = V_;
    for (int i = lane; i < 157; i += 64) {
        float2 pm = cload2(pargmax + ((size_t)b * 157 + i) * 2);
        int idx = (int)pm.y;
        if (pm.x > best || (pm.x == best && idx < bi)) { best = pm.x; bi = idx; }
    }
#pragma unroll
    for (int m = 32; m >= 1; m >>= 1) {
        float ob = __shfl_xor(best, m, 64);
        int oi = __shfl_xor(bi, m, 64);
        if (ob > best || (ob == best && oi < bi)) { best = ob; bi = oi; }
    }
    const float4* e4 = (const float4*)(emb + (size_t)bi * 512);
    float4 v0 = e4[lane], v1 = e4[lane + 64];
    float* xp = X + (size_t)b * XSTR + 2048;
    cstore2(xp + lane * 4,           make_float2(v0.x, v0.y));
    cstore2(xp + lane * 4 + 2,       make_float2(v0.z, v0.w));
    cstore2(xp + 256 + lane * 4,     make_float2(v1.x, v1.y));
    cstore2(xp + 256 + lane * 4 + 2, make_float2(v1.z, v1.w));
}

// ctx accumulate only: all 256 blocks, b=bid>>2, dq=bid&3 (512 d each).
// att staged from attbuf (coherent); enc non-temporal streaming.
__device__ __forceinline__ void ph_ctx2(int bid, int tid, const float* enc,
                                        const float* attbuf, float* X,
                                        float* s_att) {
    int b = bid >> 2, dq = bid & 3;
    if (tid < P_) s_att[tid] = cload(attbuf + b * 256 + tid);
    __syncthreads();
    int d = dq * 512 + tid * 2;
    const float* base = enc + (size_t)b * P_ * ENC_ + d;
    float a0 = 0, a1 = 0, a2 = 0, a3 = 0;
    float c0 = 0, c1 = 0, c2 = 0, c3 = 0;
#pragma unroll 2
    for (int p = 0; p < P_; p += 4) {
        float w0 = s_att[p + 0], w1 = s_att[p + 1];
        float w2 = s_att[p + 2], w3 = s_att[p + 3];
        float2 v0 = ntload2(base + (size_t)(p + 0) * ENC_);
        float2 v1 = ntload2(base + (size_t)(p + 1) * ENC_);
        float2 v2 = ntload2(base + (size_t)(p + 2) * ENC_);
        float2 v3 = ntload2(base + (size_t)(p + 3) * ENC_);
        a0 = fmaf(w0, v0.x, a0); c0 = fmaf(w0, v0.y, c0);
        a1 = fmaf(w1, v1.x, a1); c1 = fmaf(w1, v1.y, c1);
        a2 = fmaf(w2, v2.x, a2); c2 = fmaf(w2, v2.y, c2);
        a3 = fmaf(w3, v3.x, a3); c3 = fmaf(w3, v3.y, c3);
    }
    float2 o;
    o.x = (a0 + a1) + (a2 + a3);
    o.y = (c0 + c1) + (c2 + c3);
    cstore2(X + (size_t)b * XSTR + d, o);
}

// ---------------------------------------------------------------------------
// k_mega: 30-step decode loop, persistent, 5 grid barriers/step.
// A gates | B lstm | C logits+argmax || att2 | D e+softmax || fin | E ctx
// ---------------------------------------------------------------------------
__global__ __launch_bounds__(256) void k_mega(
    const float* __restrict__ enc, const float* __restrict__ emb,
    const float* __restrict__ Wd, const float* __restrict__ bd,
    const float* __restrict__ Wf, const float* __restrict__ bfp,
    const float* __restrict__ Wih, const float* __restrict__ bih,
    const float* __restrict__ Whh, const float* __restrict__ bhh,
    const float* __restrict__ Wv, const float* __restrict__ bv,
    const float* __restrict__ att1, float* __restrict__ X,
    float* __restrict__ cbuf, float* __restrict__ att2buf,
    float* __restrict__ attbuf, float* __restrict__ pargmax,
    float* __restrict__ pg, float* __restrict__ out,
    float* __restrict__ atts_out, unsigned* __restrict__ bar,
    int kcT, int chunk) {
    const int bid = blockIdx.x, tid = threadIdx.x;
    const int wid = tid >> 6, lane = tid & 63;
    __shared__ __align__(16) float s_stage[64 * SUBCH];  // 128 KiB
    __shared__ __align__(16) float s_att2[512];
    __shared__ float s_e[256];
    __shared__ float s_red[256];
    __shared__ float s_att[256];
    unsigned* flags = bar;
    unsigned* gen = bar + 256;
    unsigned seq = 1;

    // prologue: att2_0 -> e/softmax_0 -> ctx_0
    ph_hstage(bid >= 157 && bid < 173, wid, lane, X, s_stage);
    if (bid >= 157 && bid < 173) ph_att2c(bid, wid, lane, s_stage, Wd, bd, att2buf);
    gbar(flags, gen, seq); seq++;
    if (bid < 64)
        ph_e(bid, tid, wid, lane, att1, att2buf, Wf, bfp, attbuf, atts_out, 0,
             s_att2, s_e, s_red);
    gbar(flags, gen, seq); seq++;
    ph_ctx2(bid, tid, enc, attbuf, X, s_att);
    gbar(flags, gen, seq); seq++;

#pragma unroll 1
    for (int t = 0; t < L_; ++t) {
        // A: gates
        ph_gates(bid, tid, wid, lane, X, Wih, Whh, pg, kcT, chunk, s_stage);
        gbar(flags, gen, seq); seq++;
        // B: lstm
        ph_lstm(bid, tid, pg, bih, bhh, X, cbuf, kcT);
        gbar(flags, gen, seq); seq++;
        // C: logits_t (+argmax partials) || att2_{t+1}
        ph_hstage(bid < 173, wid, lane, X, s_stage);
        if (bid < 157) ph_logits(bid, wid, lane, s_stage, Wv, bv, out, pargmax, t);
        else if (bid < 173 && t < L_ - 1)
            ph_att2c(bid, wid, lane, s_stage, Wd, bd, att2buf);
        if (t == L_ - 1) break;   // uniform exit; pending stores drain at kernel end
        gbar(flags, gen, seq); seq++;
        // D: e/softmax_{t+1} || fin_t
        if (bid < 64)
            ph_e(bid, tid, wid, lane, att1, att2buf, Wf, bfp, attbuf, atts_out,
                 t + 1, s_att2, s_e, s_red);
        else if (bid >= 200 && bid < 216)
            ph_fin(bid, wid, lane, pargmax, emb, X);
        gbar(flags, gen, seq); seq++;
        // E: ctx_{t+1}
        ph_ctx2(bid, tid, enc, attbuf, X, s_att);
        gbar(flags, gen, seq); seq++;
    }
}

// ---------------------------------------------------------------------------
extern "C" void kernel_launch(void* const* d_in, const int* in_sizes, int n_in,
                              void* d_out, int out_size, void* d_ws, size_t ws_size,
                              hipStream_t stream) {
    const float* enc = (const float*)d_in[0];
    const int* dec   = (const int*)d_in[1];
    const float* emb = (const float*)d_in[3];
    const float* We  = (const float*)d_in[4];
    const float* be  = (const float*)d_in[5];
    const float* Wd  = (const float*)d_in[6];
    const float* bd  = (const float*)d_in[7];
    const float* Wf  = (const float*)d_in[8];
    const float* bf  = (const float*)d_in[9];
    const float* Wih = (const float*)d_in[10];
    const float* bih = (const float*)d_in[11];
    const float* Whh = (const float*)d_in[12];
    const float* bhh = (const float*)d_in[13];
    const float* Wh0 = (const float*)d_in[14];
    const float* bh0 = (const float*)d_in[15];
    const float* Wc0 = (const float*)d_in[16];
    const float* bc0 = (const float*)d_in[17];
    const float* Wv  = (const float*)d_in[18];
    const float* bv  = (const float*)d_in[19];

    float* out = (float*)d_out;
    float* ws = (float*)d_ws;

    // workspace layout (floats)
    float* att1    = ws;                    // 6,422,528
    float* X       = att1 + 6422528;        //   196,608
    float* cbuf    = X + 196608;            //    32,768
    float* att2buf = cbuf + 32768;          //    32,768
    float* attbuf  = att2buf + 32768;       //    16,384 (64 x 256)
    float* pargmax = attbuf + 16384;        //    20,480 (64 x 157 x2, padded)
    unsigned* bar  = (unsigned*)(pargmax + 20480);  // 512 slot (257 used)
    float* pg      = ws + 6722048;          // kcT * 131,072 gate partials
    float* mean    = pg;                    // alias: only live before k_mega

    const size_t base_fl = 6722048;
    size_t avail_fl = ws_size / 4;
    int kcT = 2, chunk = 1536;
    const int opt_kc[5] = {32, 16, 8, 4, 2};
    for (int i = 0; i < 5; i++) {
        if (avail_fl >= base_fl + (size_t)opt_kc[i] * 131072) {
            kcT = opt_kc[i];
            chunk = 3072 / kcT;
            break;
        }
    }

    float* atts_out = out + (size_t)B_ * L_ * V_;

    hipLaunchKernelGGL(k_init, dim3(8, 64), dim3(256), 0, stream, enc, mean, bar);
    hipLaunchKernelGGL(k_big, dim3(400), dim3(256), 0, stream, enc, mean, We, be,
                       Wh0, bh0, Wc0, bc0, att1, X, cbuf);
    hipLaunchKernelGGL(k_emb0, dim3(64), dim3(256), 0, stream, emb, dec, X);
    hipLaunchKernelGGL(k_mega, dim3(NB), dim3(256), 0, stream,
                       enc, emb, Wd, bd, Wf, bf, Wih, bih, Whh, bhh, Wv, bv,
                       att1, X, cbuf, att2buf, attbuf, pargmax, pg, out,
                       atts_out, bar, kcT, chunk);
}

// Round 4
// 4292.951 us; speedup vs baseline: 2.8065x; 1.6643x over previous
//
#include <hip/hip_runtime.h>
#include <math.h>

constexpr int B_   = 64;
constexpr int L_   = 30;
constexpr int P_   = 196;
constexpr int ENC_ = 2048;
constexpr int V_   = 10000;
constexpr int XSTR = 3072;   // X row: [ctx 2048 | emb 512 | h 512]
constexpr unsigned NB = 256; // persistent grid size (1 block/CU)
constexpr int SUBCH = 512;   // gates staging sub-chunk (floats)

__device__ __forceinline__ float sigmf(float x) { return 1.0f / (1.0f + expf(-x)); }

// 16-term dot: w[4] (registers) . x[16] (pointer, 16B-aligned; global or LDS)
__device__ __forceinline__ float dot16(const float4* w, const float* xp) {
    const float4* x4 = (const float4*)xp;
    float4 x0 = x4[0], x1 = x4[1], x2 = x4[2], x3 = x4[3];
    float s = w[0].x * x0.x;
    s = fmaf(w[0].y, x0.y, s); s = fmaf(w[0].z, x0.z, s); s = fmaf(w[0].w, x0.w, s);
    s = fmaf(w[1].x, x1.x, s); s = fmaf(w[1].y, x1.y, s);
    s = fmaf(w[1].z, x1.z, s); s = fmaf(w[1].w, x1.w, s);
    s = fmaf(w[2].x, x2.x, s); s = fmaf(w[2].y, x2.y, s);
    s = fmaf(w[2].z, x2.z, s); s = fmaf(w[2].w, x2.w, s);
    s = fmaf(w[3].x, x3.x, s); s = fmaf(w[3].y, x3.y, s);
    s = fmaf(w[3].z, x3.z, s); s = fmaf(w[3].w, x3.w, s);
    return s;
}

// --------------------------------------------------------------------------
// Coherent (L2-bypassing) accessors for cross-block state.
// --------------------------------------------------------------------------
__device__ __forceinline__ float2 cload2(const float* p) {
    unsigned long long v = __hip_atomic_load((const unsigned long long*)p,
                                             __ATOMIC_RELAXED, __HIP_MEMORY_SCOPE_AGENT);
    union { unsigned long long u; float2 f; } c; c.u = v; return c.f;
}
__device__ __forceinline__ void cstore2(float* p, float2 v) {
    union { float2 f; unsigned long long u; } c; c.f = v;
    __hip_atomic_store((unsigned long long*)p, c.u,
                       __ATOMIC_RELAXED, __HIP_MEMORY_SCOPE_AGENT);
}
__device__ __forceinline__ float cload(const float* p) {
    unsigned v = __hip_atomic_load((const unsigned*)p,
                                   __ATOMIC_RELAXED, __HIP_MEMORY_SCOPE_AGENT);
    return __uint_as_float(v);
}
__device__ __forceinline__ void cstore(float* p, float v) {
    __hip_atomic_store((unsigned*)p, __float_as_uint(v),
                       __ATOMIC_RELAXED, __HIP_MEMORY_SCOPE_AGENT);
}
// non-temporal 16B load (no L2 allocate) for streaming enc reads
__device__ __forceinline__ float4 ntload4(const float* p) {
    typedef float v4f __attribute__((ext_vector_type(4)));
    v4f t = __builtin_nontemporal_load((const v4f*)p);
    return make_float4(t.x, t.y, t.z, t.w);
}

// --------------------------------------------------------------------------
// Fence-free grid barrier (proven round 2/3).
// --------------------------------------------------------------------------
__device__ __forceinline__ void gbar(unsigned* flags, unsigned* gen, unsigned seq) {
    asm volatile("s_waitcnt vmcnt(0)" ::: "memory");
    __syncthreads();
    if (blockIdx.x == 0) {
        int i = threadIdx.x;
        if (i >= 1 && i < (int)NB) {
            while (__hip_atomic_load(&flags[i], __ATOMIC_RELAXED,
                                     __HIP_MEMORY_SCOPE_AGENT) < seq)
                __builtin_amdgcn_s_sleep(4);
        }
        __syncthreads();
        if (i == 0)
            __hip_atomic_store(gen, seq, __ATOMIC_RELAXED, __HIP_MEMORY_SCOPE_AGENT);
    } else {
        if (threadIdx.x == 0) {
            __hip_atomic_store(&flags[blockIdx.x], seq,
                               __ATOMIC_RELAXED, __HIP_MEMORY_SCOPE_AGENT);
            while (__hip_atomic_load(gen, __ATOMIC_RELAXED,
                                     __HIP_MEMORY_SCOPE_AGENT) < seq)
                __builtin_amdgcn_s_sleep(4);
        }
        __syncthreads();
    }
    asm volatile("" ::: "memory");
}

// ---------------------------------------------------------------------------
// k_init: mean over P  (+ zero barrier flags).  grid=(8,64), 256 thr.
// ---------------------------------------------------------------------------
__global__ __launch_bounds__(256) void k_init(const float* __restrict__ enc,
                                              float* __restrict__ mean,
                                              unsigned* __restrict__ bar) {
    if (blockIdx.x == 0 && blockIdx.y == 0) {
        bar[threadIdx.x] = 0u;
        if (threadIdx.x == 0) bar[256] = 0u;
    }
    int dc = blockIdx.x, b = blockIdx.y, d = dc * 256 + threadIdx.x;
    const float* base = enc + (size_t)b * P_ * ENC_ + d;
    float s = 0.f;
    for (int p = 0; p < P_; p++) s += base[(size_t)p * ENC_];
    mean[(size_t)b * ENC_ + d] = s / 196.0f;
}

// ---------------------------------------------------------------------------
// k_big: fp32 GEMM, 128x128 tile, BK=16, split 8x8 micro-tile. (unchanged)
// ---------------------------------------------------------------------------
__global__ __launch_bounds__(256) void k_big(
    const float* __restrict__ enc, const float* __restrict__ mean,
    const float* __restrict__ We, const float* __restrict__ be,
    const float* __restrict__ Wh0, const float* __restrict__ bh0,
    const float* __restrict__ Wc0, const float* __restrict__ bc0,
    float* __restrict__ att1, float* __restrict__ X, float* __restrict__ cbuf) {
    __shared__ __align__(16) float As[16][132];
    __shared__ __align__(16) float Ws[16][132];
    int gx = blockIdx.x;
    const float *A, *W, *bias;
    float* C;
    int m0, n0, Mtot, cstr;
    if (gx < 392) {
        A = enc; W = We; bias = be; C = att1;
        m0 = (gx >> 2) * 128; n0 = (gx & 3) * 128; Mtot = 12544; cstr = 512;
    } else if (gx < 396) {
        A = mean; W = Wh0; bias = bh0; C = X + 2560;
        m0 = 0; n0 = (gx - 392) * 128; Mtot = 64; cstr = XSTR;
    } else {
        A = mean; W = Wc0; bias = bc0; C = cbuf;
        m0 = 0; n0 = (gx - 396) * 128; Mtot = 64; cstr = 512;
    }
    int tid = threadIdx.x, tx = tid & 15, ty = tid >> 4;
    int srow = tid >> 2, skq = tid & 3;
    float acc[2][2][4][4] = {};
    int r0 = m0 + min(srow, Mtot - 1);
    int r1 = m0 + min(srow + 64, Mtot - 1);
    const float* a0p = A + (size_t)r0 * 2048 + skq * 4;
    const float* a1p = A + (size_t)r1 * 2048 + skq * 4;
    const float* w0p = W + (size_t)(n0 + srow) * 2048 + skq * 4;
    const float* w1p = W + (size_t)(n0 + srow + 64) * 2048 + skq * 4;
    for (int kk = 0; kk < 2048; kk += 16) {
        float4 a0v = *(const float4*)(a0p + kk);
        float4 a1v = *(const float4*)(a1p + kk);
        float4 w0v = *(const float4*)(w0p + kk);
        float4 w1v = *(const float4*)(w1p + kk);
        __syncthreads();
        As[skq * 4 + 0][srow] = a0v.x; As[skq * 4 + 1][srow] = a0v.y;
        As[skq * 4 + 2][srow] = a0v.z; As[skq * 4 + 3][srow] = a0v.w;
        As[skq * 4 + 0][srow + 64] = a1v.x; As[skq * 4 + 1][srow + 64] = a1v.y;
        As[skq * 4 + 2][srow + 64] = a1v.z; As[skq * 4 + 3][srow + 64] = a1v.w;
        Ws[skq * 4 + 0][srow] = w0v.x; Ws[skq * 4 + 1][srow] = w0v.y;
        Ws[skq * 4 + 2][srow] = w0v.z; Ws[skq * 4 + 3][srow] = w0v.w;
        Ws[skq * 4 + 0][srow + 64] = w1v.x; Ws[skq * 4 + 1][srow + 64] = w1v.y;
        Ws[skq * 4 + 2][srow + 64] = w1v.z; Ws[skq * 4 + 3][srow + 64] = w1v.w;
        __syncthreads();
#pragma unroll
        for (int k = 0; k < 16; k++) {
            float4 av0 = *(const float4*)&As[k][ty * 4];
            float4 av1 = *(const float4*)&As[k][64 + ty * 4];
            float4 bv0 = *(const float4*)&Ws[k][tx * 4];
            float4 bv1 = *(const float4*)&Ws[k][64 + tx * 4];
            float ar[2][4] = {{av0.x, av0.y, av0.z, av0.w}, {av1.x, av1.y, av1.z, av1.w}};
            float br[2][4] = {{bv0.x, bv0.y, bv0.z, bv0.w}, {bv1.x, bv1.y, bv1.z, bv1.w}};
#pragma unroll
            for (int ih = 0; ih < 2; ih++)
#pragma unroll
                for (int jh = 0; jh < 2; jh++)
#pragma unroll
                    for (int i = 0; i < 4; i++)
#pragma unroll
                        for (int j = 0; j < 4; j++)
                            acc[ih][jh][i][j] = fmaf(ar[ih][i], br[jh][j], acc[ih][jh][i][j]);
        }
    }
#pragma unroll
    for (int ih = 0; ih < 2; ih++)
#pragma unroll
        for (int i = 0; i < 4; i++) {
            int m = m0 + ih * 64 + ty * 4 + i;
            if (m - m0 < Mtot) {
#pragma unroll
                for (int jh = 0; jh < 2; jh++) {
                    int n = n0 + jh * 64 + tx * 4;
                    float4 o;
                    o.x = acc[ih][jh][i][0] + bias[n + 0];
                    o.y = acc[ih][jh][i][1] + bias[n + 1];
                    o.z = acc[ih][jh][i][2] + bias[n + 2];
                    o.w = acc[ih][jh][i][3] + bias[n + 3];
                    *(float4*)(C + (size_t)m * cstr + n) = o;
                }
            }
        }
}

// ---------------------------------------------------------------------------
// k_emb0: X emb-slot <- emb[dec_in[:,0]].  grid=64, 256 thr.
// ---------------------------------------------------------------------------
__global__ __launch_bounds__(256) void k_emb0(const float* __restrict__ emb,
                                              const int* __restrict__ dec,
                                              float* __restrict__ X) {
    int b = blockIdx.x, tid = threadIdx.x;
    int tok = dec[b * L_];
    X[(size_t)b * XSTR + 2048 + tid] = emb[(size_t)tok * 512 + tid];
    X[(size_t)b * XSTR + 2048 + 256 + tid] = emb[(size_t)tok * 512 + 256 + tid];
}

// ===========================================================================
// Persistent mega-kernel phases. Grid = 256 blocks x 512 thr (8 waves/block).
// ===========================================================================

// gates: wave-task = (nt, kc, bhalf). Block = fixed (kc,bhalf), 8 nt-waves.
// acc[32] per lane; X chunk for 32 batches staged coherent into LDS.
__device__ __forceinline__ void ph_gates(int bid, int tid, int wid, int lane,
                                         const float* X, const float* Wih,
                                         const float* Whh, float* pg,
                                         int kcT, int chunk, float* s_stage) {
    bool act = (bid < 8 * kcT);
    int nthigh = bid & 3;
    int kc = (bid >> 2) & (kcT - 1);
    int bh = act ? ((bid >> 2) / kcT) : 0;  // 0 or 1
    int nt = nthigh * 8 + wid;
    int row = nt * 64 + lane;
    const float* wih_row = Wih + (size_t)row * 2560;
    const float* whh_row = Whh + (size_t)row * 512;
    int kbase = kc * chunk;
    float acc[32];
#pragma unroll
    for (int b = 0; b < 32; b++) acc[b] = 0.f;
    for (int sc = 0; sc < chunk; sc += SUBCH) {
        int cl = min(SUBCH, chunk - sc);
        if (act) {
            int hcl = cl >> 1;
            for (int bb = wid * 4; bb < wid * 4 + 4; bb++) {
                const float* xr = X + (size_t)(bh * 32 + bb) * XSTR + kbase + sc;
                float* sr = s_stage + bb * SUBCH;
                for (int j2 = lane; j2 < hcl; j2 += 64)
                    *(float2*)&sr[j2 * 2] = cload2(xr + j2 * 2);
            }
        }
        __syncthreads();
        if (act) {
#pragma unroll 1
            for (int k16 = sc; k16 < sc + cl; k16 += 16) {
                int kk = kbase + k16;
                const float* wr = (kk < 2560) ? (wih_row + kk) : (whh_row + (kk - 2560));
                float4 w[4];
                w[0] = *(const float4*)(wr);
                w[1] = *(const float4*)(wr + 4);
                w[2] = *(const float4*)(wr + 8);
                w[3] = *(const float4*)(wr + 12);
                const float* xc = s_stage + (k16 - sc);
#pragma unroll
                for (int b = 0; b < 32; b++)
                    acc[b] += dot16(w, xc + b * SUBCH);
            }
        }
        __syncthreads();
    }
    if (act) {
        float* prow = pg + ((size_t)kc * 64 + bh * 32) * 2048 + row;
#pragma unroll
        for (int b = 0; b < 32; b++)
            cstore(prow + (size_t)b * 2048, acc[b]);
    }
}

// lstm: 128 blocks (b = bid>>1, jh = bid&1). Gate-pair split across thread
// halves, recombined in LDS. cbuf block-private (stable CU mapping).
__device__ __forceinline__ void ph_lstm(int bid, int tid, const float* pg,
                                        const float* bih, const float* bhh,
                                        float* X, float* cbuf, int kcT,
                                        float* s_g) {
    if (bid >= 128) return;
    int b = bid >> 1, jh = bid & 1;
    int jl = tid & 255, gi2 = tid >> 8;
    int j = jh * 256 + jl;
#pragma unroll
    for (int gg = 0; gg < 2; gg++) {
        int gi = gi2 * 2 + gg;
        int n = gi * 512 + j;
        float s = bih[n] + bhh[n];
#pragma unroll 4
        for (int kc = 0; kc < kcT; kc++)
            s += cload(pg + ((size_t)kc * 64 + b) * 2048 + n);
        s_g[gi * 256 + jl] = s;
    }
    __syncthreads();
    if (gi2 == 0) {
        float gi_ = s_g[0 * 256 + jl], gf = s_g[1 * 256 + jl];
        float gc = s_g[2 * 256 + jl], go = s_g[3 * 256 + jl];
        float c = cbuf[b * 512 + j];
        float cn = sigmf(gf) * c + sigmf(gi_) * tanhf(gc);
        float hn = sigmf(go) * tanhf(cn);
        cbuf[b * 512 + j] = cn;
        cstore(X + (size_t)b * XSTR + 2560 + j, hn);
    }
}

// stage h (all 64 b, 128KB) coherently into LDS. 8 waves x 8 b.
__device__ __forceinline__ void ph_hstage(bool act, int wid, int lane,
                                          const float* X, float* s_stage) {
    if (act) {
        for (int b = wid * 8; b < wid * 8 + 8; b++) {
            const float* xr = X + (size_t)b * XSTR + 2560;
            float* sr = s_stage + b * 512;
            for (int j2 = lane; j2 < 256; j2 += 64)
                *(float2*)&sr[j2 * 2] = cload2(xr + j2 * 2);
        }
    }
    __syncthreads();
}

// logits: blocks 0..156, wave wid handles 8 batches. out plain (host-only);
// per-(b,segment) argmax partials coherent.
__device__ __forceinline__ void ph_logits(int bid, int wid, int lane,
                                          const float* s_stage, const float* Wv,
                                          const float* bv, float* out,
                                          float* pargmax, int t) {
    int v = bid * 64 + lane;
    int vr = min(v, V_ - 1);
    const float* wrow = Wv + (size_t)vr * 512;
    const float* xbase = s_stage + wid * 8 * 512;
    float acc[8];
#pragma unroll
    for (int b = 0; b < 8; b++) acc[b] = 0.f;
#pragma unroll 1
    for (int k16 = 0; k16 < 512; k16 += 16) {
        float4 w[4];
        w[0] = *(const float4*)(wrow + k16);
        w[1] = *(const float4*)(wrow + k16 + 4);
        w[2] = *(const float4*)(wrow + k16 + 8);
        w[3] = *(const float4*)(wrow + k16 + 12);
        const float* xc = xbase + k16;
#pragma unroll
        for (int b = 0; b < 8; b++)
            acc[b] += dot16(w, xc + b * 512);
    }
    float bias = bv[vr];
#pragma unroll
    for (int b = 0; b < 8; b++) {
        float val = acc[b] + bias;
        int bb = wid * 8 + b;
        if (v < V_) out[((size_t)bb * L_ + t) * V_ + v] = val;
        float mval = (v < V_) ? val : -INFINITY;
        int midx = v;
#pragma unroll
        for (int m = 32; m >= 1; m >>= 1) {
            float ov = __shfl_xor(mval, m, 64);
            int oi = __shfl_xor(midx, m, 64);
            if (ov > mval || (ov == mval && oi < midx)) { mval = ov; midx = oi; }
        }
        if (lane == 0)
            cstore2(pargmax + ((size_t)bb * 157 + bid) * 2,
                    make_float2(mval, (float)midx));
    }
}

// att2: blocks 157..164 (64 wave-tasks). h from LDS. stores coherent.
__device__ __forceinline__ void ph_att2c(int bid, int wid, int lane,
                                         const float* s_stage, const float* Wd,
                                         const float* bd, float* att2buf) {
    int task = (bid - 157) * 8 + wid;  // [0,64)
    int nt = task >> 3, bg = task & 7;
    int n = nt * 64 + lane;
    const float* wrow = Wd + (size_t)n * 512;
    const float* xbase = s_stage + bg * 8 * 512;
    float acc[8];
#pragma unroll
    for (int b = 0; b < 8; b++) acc[b] = 0.f;
#pragma unroll 1
    for (int k16 = 0; k16 < 512; k16 += 16) {
        float4 w[4];
        w[0] = *(const float4*)(wrow + k16);
        w[1] = *(const float4*)(wrow + k16 + 4);
        w[2] = *(const float4*)(wrow + k16 + 8);
        w[3] = *(const float4*)(wrow + k16 + 12);
        const float* xc = xbase + k16;
#pragma unroll
        for (int b = 0; b < 8; b++)
            acc[b] += dot16(w, xc + b * 512);
    }
    float bias = bd[n];
#pragma unroll
    for (int b = 0; b < 8; b++)
        cstore(att2buf + (size_t)(bg * 8 + b) * 512 + n, acc[b] + bias);
}

// e + softmax for ONE b per block (blocks 0..63), 8 waves over p.
__device__ __forceinline__ void ph_e(int bid, int tid, int wid, int lane,
                                     const float* att1, const float* att2buf,
                                     const float* Wf, const float* bfp,
                                     float* attbuf, float* atts_out, int t,
                                     float* s_att2, float* s_e, float* s_red) {
    int b = bid;
    if (tid < 256)
        *(float2*)&s_att2[tid * 2] = cload2(att2buf + (size_t)b * 512 + tid * 2);
    __syncthreads();
    const float4* a24 = (const float4*)s_att2;
    float4 t0 = a24[lane], t1 = a24[lane + 64];
    const float4* wf4 = (const float4*)Wf;
    float4 f0 = wf4[lane], f1 = wf4[lane + 64];
    float bfv = bfp[0];
    for (int p = wid; p < P_; p += 8) {
        const float4* rr = (const float4*)(att1 + ((size_t)b * P_ + p) * 512);
        float4 v0 = rr[lane], v1 = rr[lane + 64];
        float s = fmaxf(v0.x + t0.x, 0.f) * f0.x + fmaxf(v0.y + t0.y, 0.f) * f0.y +
                  fmaxf(v0.z + t0.z, 0.f) * f0.z + fmaxf(v0.w + t0.w, 0.f) * f0.w +
                  fmaxf(v1.x + t1.x, 0.f) * f1.x + fmaxf(v1.y + t1.y, 0.f) * f1.y +
                  fmaxf(v1.z + t1.z, 0.f) * f1.z + fmaxf(v1.w + t1.w, 0.f) * f1.w;
#pragma unroll
        for (int m = 32; m >= 1; m >>= 1) s += __shfl_xor(s, m, 64);
        if (lane == 0) s_e[p] = s + bfv;
    }
    __syncthreads();
    float val = -INFINITY;
    if (tid < 256) {
        val = (tid < P_) ? s_e[tid] : -INFINITY;
        s_red[tid] = val;
    }
    __syncthreads();
    for (int s = 128; s > 0; s >>= 1) {
        if (tid < s) s_red[tid] = fmaxf(s_red[tid], s_red[tid + s]);
        __syncthreads();
    }
    float m = s_red[0];
    __syncthreads();
    float ex = (tid < P_) ? expf(val - m) : 0.f;
    if (tid < 256) s_red[tid] = ex;
    __syncthreads();
    for (int s = 128; s > 0; s >>= 1) {
        if (tid < s) s_red[tid] += s_red[tid + s];
        __syncthreads();
    }
    float sum = s_red[0];
    if (tid < P_) {
        float att = ex / sum;
        cstore(attbuf + b * 256 + tid, att);
        atts_out[((size_t)b * L_ + t) * P_ + tid] = att;
    }
}

// fin: blocks 200..207, wave = one b. Reduce 157 argmax partials; emb -> X.
__device__ __forceinline__ void ph_fin(int bid, int wid, int lane,
                                       const float* pargmax, const float* emb,
                                       float* X) {
    int b = (bid - 200) * 8 + wid;
    float best = -INFINITY;
    int bi = V_;
    for (int i = lane; i < 157; i += 64) {
        float2 pm = cload2(pargmax + ((size_t)b * 157 + i) * 2);
        int idx = (int)pm.y;
        if (pm.x > best || (pm.x == best && idx < bi)) { best = pm.x; bi = idx; }
    }
#pragma unroll
    for (int m = 32; m >= 1; m >>= 1) {
        float ob = __shfl_xor(best, m, 64);
        int oi = __shfl_xor(bi, m, 64);
        if (ob > best || (ob == best && oi < bi)) { best = ob; bi = oi; }
    }
    const float4* e4 = (const float4*)(emb + (size_t)bi * 512);
    float4 v0 = e4[lane], v1 = e4[lane + 64];
    float* xp = X + (size_t)b * XSTR + 2048;
    cstore2(xp + lane * 4,           make_float2(v0.x, v0.y));
    cstore2(xp + lane * 4 + 2,       make_float2(v0.z, v0.w));
    cstore2(xp + 256 + lane * 4,     make_float2(v1.x, v1.y));
    cstore2(xp + 256 + lane * 4 + 2, make_float2(v1.z, v1.w));
}

// ctx accumulate: 256 blocks = 64 b x 4 dq (512 d each). 512 thr =
// 128 d-lanes (float4) x 4 p-groups; LDS combine (same association as ref).
__device__ __forceinline__ void ph_ctx2(int bid, int tid, const float* enc,
                                        const float* attbuf, float* X,
                                        float* s_att, float* s_stage) {
    int b = bid >> 2, dq = bid & 3;
    if (tid < P_) s_att[tid] = cload(attbuf + b * 256 + tid);
    __syncthreads();
    int dl = tid & 127, pg4 = tid >> 7;
    int d = dq * 512 + dl * 4;
    const float* base = enc + (size_t)b * P_ * ENC_ + d;
    float4 acc = make_float4(0.f, 0.f, 0.f, 0.f);
#pragma unroll 7
    for (int p = pg4; p < P_; p += 4) {
        float w = s_att[p];
        float4 v = ntload4(base + (size_t)p * ENC_);
        acc.x = fmaf(w, v.x, acc.x);
        acc.y = fmaf(w, v.y, acc.y);
        acc.z = fmaf(w, v.z, acc.z);
        acc.w = fmaf(w, v.w, acc.w);
    }
    float4* sc4 = (float4*)s_stage;
    sc4[pg4 * 128 + dl] = acc;
    __syncthreads();
    if (tid < 128) {
        float4 r0 = sc4[tid], r1 = sc4[128 + tid];
        float4 r2 = sc4[256 + tid], r3 = sc4[384 + tid];
        float4 o;
        o.x = (r0.x + r1.x) + (r2.x + r3.x);
        o.y = (r0.y + r1.y) + (r2.y + r3.y);
        o.z = (r0.z + r1.z) + (r2.z + r3.z);
        o.w = (r0.w + r1.w) + (r2.w + r3.w);
        float* xp = X + (size_t)b * XSTR + dq * 512 + tid * 4;
        cstore2(xp,     make_float2(o.x, o.y));
        cstore2(xp + 2, make_float2(o.z, o.w));
    }
    __syncthreads();
}

// ---------------------------------------------------------------------------
// k_mega: 30-step decode loop, persistent, 5 grid barriers/step, 8 waves.
// A gates | B lstm | C logits+argmax || att2 | D e+softmax || fin | E ctx
// ---------------------------------------------------------------------------
__global__ __launch_bounds__(512, 2) void k_mega(
    const float* __restrict__ enc, const float* __restrict__ emb,
    const float* __restrict__ Wd, const float* __restrict__ bd,
    const float* __restrict__ Wf, const float* __restrict__ bfp,
    const float* __restrict__ Wih, const float* __restrict__ bih,
    const float* __restrict__ Whh, const float* __restrict__ bhh,
    const float* __restrict__ Wv, const float* __restrict__ bv,
    const float* __restrict__ att1, float* __restrict__ X,
    float* __restrict__ cbuf, float* __restrict__ att2buf,
    float* __restrict__ attbuf, float* __restrict__ pargmax,
    float* __restrict__ pg, float* __restrict__ out,
    float* __restrict__ atts_out, unsigned* __restrict__ bar,
    int kcT, int chunk) {
    const int bid = blockIdx.x, tid = threadIdx.x;
    const int wid = tid >> 6, lane = tid & 63;
    __shared__ __align__(16) float s_stage[64 * SUBCH];  // 128 KiB
    __shared__ __align__(16) float s_att2[512];
    __shared__ float s_e[256];
    __shared__ float s_red[256];
    __shared__ float s_att[256];
    __shared__ float s_g[4 * 256];
    unsigned* flags = bar;
    unsigned* gen = bar + 256;
    unsigned seq = 1;

    // prologue: att2_0 -> e/softmax_0 -> ctx_0
    ph_hstage(bid >= 157 && bid < 165, wid, lane, X, s_stage);
    if (bid >= 157 && bid < 165) ph_att2c(bid, wid, lane, s_stage, Wd, bd, att2buf);
    gbar(flags, gen, seq); seq++;
    if (bid < 64)
        ph_e(bid, tid, wid, lane, att1, att2buf, Wf, bfp, attbuf, atts_out, 0,
             s_att2, s_e, s_red);
    gbar(flags, gen, seq); seq++;
    ph_ctx2(bid, tid, enc, attbuf, X, s_att, s_stage);
    gbar(flags, gen, seq); seq++;

#pragma unroll 1
    for (int t = 0; t < L_; ++t) {
        // A: gates
        ph_gates(bid, tid, wid, lane, X, Wih, Whh, pg, kcT, chunk, s_stage);
        gbar(flags, gen, seq); seq++;
        // B: lstm
        ph_lstm(bid, tid, pg, bih, bhh, X, cbuf, kcT, s_g);
        gbar(flags, gen, seq); seq++;
        // C: logits_t (+argmax partials) || att2_{t+1}
        ph_hstage(bid < 165, wid, lane, X, s_stage);
        if (bid < 157) ph_logits(bid, wid, lane, s_stage, Wv, bv, out, pargmax, t);
        else if (bid < 165 && t < L_ - 1)
            ph_att2c(bid, wid, lane, s_stage, Wd, bd, att2buf);
        if (t == L_ - 1) break;   // uniform exit; stores drain at kernel end
        gbar(flags, gen, seq); seq++;
        // D: e/softmax_{t+1} || fin_t
        if (bid < 64)
            ph_e(bid, tid, wid, lane, att1, att2buf, Wf, bfp, attbuf, atts_out,
                 t + 1, s_att2, s_e, s_red);
        else if (bid >= 200 && bid < 208)
            ph_fin(bid, wid, lane, pargmax, emb, X);
        gbar(flags, gen, seq); seq++;
        // E: ctx_{t+1}
        ph_ctx2(bid, tid, enc, attbuf, X, s_att, s_stage);
        gbar(flags, gen, seq); seq++;
    }
}

// ---------------------------------------------------------------------------
extern "C" void kernel_launch(void* const* d_in, const int* in_sizes, int n_in,
                              void* d_out, int out_size, void* d_ws, size_t ws_size,
                              hipStream_t stream) {
    const float* enc = (const float*)d_in[0];
    const int* dec   = (const int*)d_in[1];
    const float* emb = (const float*)d_in[3];
    const float* We  = (const float*)d_in[4];
    const float* be  = (const float*)d_in[5];
    const float* Wd  = (const float*)d_in[6];
    const float* bd  = (const float*)d_in[7];
    const float* Wf  = (const float*)d_in[8];
    const float* bf  = (const float*)d_in[9];
    const float* Wih = (const float*)d_in[10];
    const float* bih = (const float*)d_in[11];
    const float* Whh = (const float*)d_in[12];
    const float* bhh = (const float*)d_in[13];
    const float* Wh0 = (const float*)d_in[14];
    const float* bh0 = (const float*)d_in[15];
    const float* Wc0 = (const float*)d_in[16];
    const float* bc0 = (const float*)d_in[17];
    const float* Wv  = (const float*)d_in[18];
    const float* bv  = (const float*)d_in[19];

    float* out = (float*)d_out;
    float* ws = (float*)d_ws;

    // workspace layout (floats)
    float* att1    = ws;                    // 6,422,528
    float* X       = att1 + 6422528;        //   196,608
    float* cbuf    = X + 196608;            //    32,768
    float* att2buf = cbuf + 32768;          //    32,768
    float* attbuf  = att2buf + 32768;       //    16,384 (64 x 256)
    float* pargmax = attbuf + 16384;        //    20,480 (64 x 157 x2, padded)
    unsigned* bar  = (unsigned*)(pargmax + 20480);  // 512 slot (257 used)
    float* pg      = ws + 6722048;          // kcT * 131,072 gate partials
    float* mean    = pg;                    // alias: only live before k_mega

    const size_t base_fl = 6722048;
    size_t avail_fl = ws_size / 4;
    int kcT = 2, chunk = 1536;
    const int opt_kc[5] = {32, 16, 8, 4, 2};
    for (int i = 0; i < 5; i++) {
        if (avail_fl >= base_fl + (size_t)opt_kc[i] * 131072) {
            kcT = opt_kc[i];
            chunk = 3072 / kcT;
            break;
        }
    }

    float* atts_out = out + (size_t)B_ * L_ * V_;

    hipLaunchKernelGGL(k_init, dim3(8, 64), dim3(256), 0, stream, enc, mean, bar);
    hipLaunchKernelGGL(k_big, dim3(400), dim3(256), 0, stream, enc, mean, We, be,
                       Wh0, bh0, Wc0, bc0, att1, X, cbuf);
    hipLaunchKernelGGL(k_emb0, dim3(64), dim3(256), 0, stream, emb, dec, X);
    hipLaunchKernelGGL(k_mega, dim3(NB), dim3(512), 0, stream,
                       enc, emb, Wd, bd, Wf, bf, Wih, bih, Whh, bhh, Wv, bv,
                       att1, X, cbuf, att2buf, attbuf, pargmax, pg, out,
                       atts_out, bar, kcT, chunk);
}